// Round 1
// baseline (835.016 us; speedup 1.0000x reference)
//
#include <hip/hip_runtime.h>
#include <math.h>

#define N_NODES 100000
#define R 32
#define E_EDGES 3200000
#define F_IN 128
#define HDIM 16
#define CDIM 8
#define NOUT 512  // R * HDIM

// ---------------- degree histogram ----------------
__global__ __launch_bounds__(256) void k_deg(const int* __restrict__ dst,
                                             const int* __restrict__ et,
                                             float* __restrict__ deg) {
    int e = blockIdx.x * 256 + threadIdx.x;
    if (e >= E_EDGES) return;
    atomicAdd(&deg[dst[e] * R + et[e]], 1.0f);
}

// ---------------- repack W1 [R,128,16] -> B [128,512] ----------------
__global__ __launch_bounds__(256) void k_bmat(const float* __restrict__ W1,
                                              float* __restrict__ B) {
    int i = blockIdx.x * 256 + threadIdx.x;  // i = f*512 + r*16 + o
    if (i >= F_IN * NOUT) return;
    int f = i >> 9;
    int j = i & 511;
    int r = j >> 4;
    int o = j & 15;
    B[i] = W1[r * (F_IN * HDIM) + f * HDIM + o];
}

// ---------------- GEMM: C[M,512] = A[M,128] @ B[128,512] ----------------
#define BM 64
#define BN 64
#define BK 32
__global__ __launch_bounds__(256) void k_gemm1(const float* __restrict__ A,
                                               const float* __restrict__ B,
                                               float* __restrict__ C,
                                               int M) {
    __shared__ float As[BK][BM + 1];  // [k][m], padded
    __shared__ float Bs[BK][BN];      // [k][n]
    int tid = threadIdx.x;
    int row0 = blockIdx.x * BM;
    int col0 = blockIdx.y * BN;
    int tx = tid & 15;   // col group 0..15
    int ty = tid >> 4;   // row group 0..15
    float acc[4][4] = {};

    for (int k0 = 0; k0 < F_IN; k0 += BK) {
        // load A tile: 64 rows x 32 k = 512 float4, 2 per thread
        #pragma unroll
        for (int i = 0; i < 2; ++i) {
            int idx = tid + i * 256;      // 0..511
            int r = idx >> 3;             // row 0..63
            int kc = (idx & 7) << 2;      // k 0,4,...,28
            float4 v = make_float4(0.f, 0.f, 0.f, 0.f);
            int grow = row0 + r;
            if (grow < M) v = *(const float4*)(A + (size_t)grow * F_IN + k0 + kc);
            As[kc + 0][r] = v.x;
            As[kc + 1][r] = v.y;
            As[kc + 2][r] = v.z;
            As[kc + 3][r] = v.w;
        }
        // load B tile: 32 k x 64 n = 512 float4, 2 per thread
        #pragma unroll
        for (int i = 0; i < 2; ++i) {
            int idx = tid + i * 256;
            int r = idx >> 4;             // k 0..31
            int c = (idx & 15) << 2;      // n 0,4,...,60
            float4 v = *(const float4*)(B + (size_t)(k0 + r) * NOUT + col0 + c);
            *(float4*)&Bs[r][c] = v;
        }
        __syncthreads();
        #pragma unroll 4
        for (int kk = 0; kk < BK; ++kk) {
            float a[4], b[4];
            #pragma unroll
            for (int i = 0; i < 4; ++i) a[i] = As[kk][ty * 4 + i];
            #pragma unroll
            for (int j = 0; j < 4; ++j) b[j] = Bs[kk][tx * 4 + j];
            #pragma unroll
            for (int i = 0; i < 4; ++i)
                #pragma unroll
                for (int j = 0; j < 4; ++j)
                    acc[i][j] += a[i] * b[j];
        }
        __syncthreads();
    }
    #pragma unroll
    for (int i = 0; i < 4; ++i) {
        int r = row0 + ty * 4 + i;
        if (r < M) {
            float4 v = make_float4(acc[i][0], acc[i][1], acc[i][2], acc[i][3]);
            *(float4*)(C + (size_t)r * NOUT + col0 + tx * 4) = v;
        }
    }
}

// ---------------- layer-1 scatter: h[dst] += xw1[src, et] * norm ----------------
__global__ __launch_bounds__(256) void k_scatter1(const int* __restrict__ src,
                                                  const int* __restrict__ dst,
                                                  const int* __restrict__ et,
                                                  const float* __restrict__ xw1,
                                                  const float* __restrict__ deg,
                                                  float* __restrict__ h) {
    long long t = (long long)blockIdx.x * 256 + threadIdx.x;
    int e = (int)(t >> 4);
    int c = (int)(t & 15);
    if (e >= E_EDGES) return;
    int s = src[e], d = dst[e], r = et[e];
    float norm = 1.0f / fmaxf(deg[d * R + r], 1.0f);
    float v = xw1[(size_t)s * NOUT + r * HDIM + c] * norm;
    atomicAdd(&h[d * HDIM + c], v);
}

// ---------------- layer-2 fused: out[dst] += (relu(h[src]) @ W2[et]) * norm ----------------
__global__ __launch_bounds__(256) void k_layer2(const int* __restrict__ src,
                                                const int* __restrict__ dst,
                                                const int* __restrict__ et,
                                                const float* __restrict__ h,
                                                const float* __restrict__ deg,
                                                const float* __restrict__ W2,
                                                float* __restrict__ out) {
    int t = blockIdx.x * 256 + threadIdx.x;
    int e = t >> 3;
    int c = t & 7;
    if (e >= E_EDGES) return;
    int s = src[e], d = dst[e], r = et[e];
    float norm = 1.0f / fmaxf(deg[d * R + r], 1.0f);
    const float* hr = h + (size_t)s * HDIM;
    const float* w = W2 + r * (HDIM * CDIM) + c;
    float4 h0 = *(const float4*)(hr);
    float4 h1 = *(const float4*)(hr + 4);
    float4 h2 = *(const float4*)(hr + 8);
    float4 h3 = *(const float4*)(hr + 12);
    float hv[16] = {h0.x, h0.y, h0.z, h0.w, h1.x, h1.y, h1.z, h1.w,
                    h2.x, h2.y, h2.z, h2.w, h3.x, h3.y, h3.z, h3.w};
    float acc = 0.f;
    #pragma unroll
    for (int k = 0; k < HDIM; ++k)
        acc += fmaxf(hv[k], 0.f) * w[k * CDIM];
    atomicAdd(&out[d * CDIM + c], acc * norm);
}

// ---------------- log_softmax rows of 8, in place ----------------
__global__ __launch_bounds__(256) void k_logsoftmax(float* __restrict__ out) {
    int n = blockIdx.x * 256 + threadIdx.x;
    if (n >= N_NODES) return;
    float4 v0 = *(float4*)(out + (size_t)n * 8);
    float4 v1 = *(float4*)(out + (size_t)n * 8 + 4);
    float m = fmaxf(fmaxf(fmaxf(v0.x, v0.y), fmaxf(v0.z, v0.w)),
                    fmaxf(fmaxf(v1.x, v1.y), fmaxf(v1.z, v1.w)));
    float s = expf(v0.x - m) + expf(v0.y - m) + expf(v0.z - m) + expf(v0.w - m) +
              expf(v1.x - m) + expf(v1.y - m) + expf(v1.z - m) + expf(v1.w - m);
    float lse = m + logf(s);
    v0.x -= lse; v0.y -= lse; v0.z -= lse; v0.w -= lse;
    v1.x -= lse; v1.y -= lse; v1.z -= lse; v1.w -= lse;
    *(float4*)(out + (size_t)n * 8) = v0;
    *(float4*)(out + (size_t)n * 8 + 4) = v1;
}

extern "C" void kernel_launch(void* const* d_in, const int* in_sizes, int n_in,
                              void* d_out, int out_size, void* d_ws, size_t ws_size,
                              hipStream_t stream) {
    const float* emb = (const float*)d_in[0];
    const float* W1  = (const float*)d_in[1];
    const float* W2  = (const float*)d_in[2];
    const int* ei    = (const int*)d_in[3];
    const int* et    = (const int*)d_in[4];
    const int* srcp  = ei;
    const int* dstp  = ei + E_EDGES;

    float* ws   = (float*)d_ws;
    float* deg  = ws;                                  // N*R        = 3.2M floats
    float* Bm   = deg + (size_t)N_NODES * R;           // 128*512    = 65536
    float* xw1  = Bm + (size_t)F_IN * NOUT;            // N*512      = 51.2M
    float* h    = xw1 + (size_t)N_NODES * NOUT;        // N*16       = 1.6M
    float* out  = (float*)d_out;

    hipMemsetAsync(deg, 0, (size_t)N_NODES * R * sizeof(float), stream);
    hipMemsetAsync(h, 0, (size_t)N_NODES * HDIM * sizeof(float), stream);
    hipMemsetAsync(d_out, 0, (size_t)N_NODES * CDIM * sizeof(float), stream);

    k_deg<<<E_EDGES / 256, 256, 0, stream>>>(dstp, et, deg);
    k_bmat<<<(F_IN * NOUT) / 256, 256, 0, stream>>>(W1, Bm);

    dim3 g_gemm((N_NODES + BM - 1) / BM, NOUT / BN);
    k_gemm1<<<g_gemm, 256, 0, stream>>>(emb, Bm, xw1, N_NODES);

    k_scatter1<<<(int)(((long long)E_EDGES * 16) / 256), 256, 0, stream>>>(
        srcp, dstp, et, xw1, deg, h);

    k_layer2<<<(E_EDGES * 8) / 256, 256, 0, stream>>>(
        srcp, dstp, et, h, deg, W2, out);

    k_logsoftmax<<<(N_NODES + 255) / 256, 256, 0, stream>>>(out);
}

// Round 2
// 693.634 us; speedup vs baseline: 1.2038x; 1.2038x over previous
//
#include <hip/hip_runtime.h>
#include <hip/hip_bf16.h>
#include <math.h>

#define N_NODES 100000
#define R 32
#define E_EDGES 3200000
#define F_IN 128
#define HDIM 16
#define CDIM 8
#define NOUT 512           // R * HDIM
#define NCHUNK 512
#define NBLK ((N_NODES + NCHUNK - 1) / NCHUNK)   // 196

typedef __attribute__((ext_vector_type(8))) short bf16x8;
typedef __attribute__((ext_vector_type(4))) float f32x4;

static __device__ __forceinline__ unsigned short f2bf(float f) {
    unsigned int u = __float_as_uint(f);
    unsigned int r = (u + 0x7FFFu + ((u >> 16) & 1u)) >> 16;
    return (unsigned short)r;
}
static __device__ __forceinline__ float bf2f(unsigned short u) {
    return __uint_as_float(((unsigned int)u) << 16);
}

// ---------------- per-(dst,rel) degree histogram (float, matches reference) ----------------
__global__ __launch_bounds__(256) void k_deg(const int* __restrict__ dst,
                                             const int* __restrict__ et,
                                             float* __restrict__ deg) {
    int e = blockIdx.x * 256 + threadIdx.x;
    if (e >= E_EDGES) return;
    atomicAdd(&deg[dst[e] * R + et[e]], 1.0f);
}

// ---------------- repack W1 [R,128,16] -> BmT bf16 [512][128] (n=r*16+o, k=f) ----------------
__global__ __launch_bounds__(256) void k_prep_w(const float* __restrict__ W1,
                                                unsigned short* __restrict__ BmT) {
    int i = blockIdx.x * 256 + threadIdx.x;   // i = n*128 + f
    if (i >= NOUT * F_IN) return;
    int n = i >> 7;
    int f = i & 127;
    int r = n >> 4;
    int o = n & 15;
    BmT[i] = f2bf(W1[r * (F_IN * HDIM) + f * HDIM + o]);
}

// ---------------- scan stage 1: node degree + per-chunk sums ----------------
__global__ __launch_bounds__(256) void k_scan1(const float* __restrict__ deg,
                                               int* __restrict__ ndeg,
                                               int* __restrict__ chunksum) {
    __shared__ int sdata[256];
    int b = blockIdx.x, t = threadIdx.x;
    int local = 0;
    #pragma unroll
    for (int j = 0; j < 2; ++j) {
        int d = b * NCHUNK + t + j * 256;
        int cnt = 0;
        if (d < N_NODES) {
            const float4* p = (const float4*)(deg + (size_t)d * R);
            float s = 0.f;
            #pragma unroll
            for (int q = 0; q < 8; ++q) { float4 v = p[q]; s += v.x + v.y + v.z + v.w; }
            cnt = (int)(s + 0.5f);
            ndeg[d] = cnt;
        }
        local += cnt;
    }
    sdata[t] = local;
    __syncthreads();
    for (int off = 128; off > 0; off >>= 1) {
        if (t < off) sdata[t] += sdata[t + off];
        __syncthreads();
    }
    if (t == 0) chunksum[b] = sdata[0];
}

// ---------------- scan stage 2: exclusive scan of chunk sums ----------------
__global__ __launch_bounds__(256) void k_scan2(const int* __restrict__ chunksum,
                                               int* __restrict__ chunkoff) {
    __shared__ int s[256];
    int t = threadIdx.x;
    s[t] = (t < NBLK) ? chunksum[t] : 0;
    __syncthreads();
    if (t == 0) {
        int acc = 0;
        for (int b = 0; b < NBLK; ++b) { int v = s[b]; s[b] = acc; acc += v; }
    }
    __syncthreads();
    if (t < NBLK) chunkoff[t] = s[t];
}

// ---------------- scan stage 3: intra-chunk exclusive scan -> rowstart ----------------
__global__ __launch_bounds__(512) void k_scan3(const int* __restrict__ ndeg,
                                               const int* __restrict__ chunkoff,
                                               int* __restrict__ rowstart) {
    __shared__ int s[NCHUNK];
    int b = blockIdx.x, t = threadIdx.x;
    int d = b * NCHUNK + t;
    int v = (d < N_NODES) ? ndeg[d] : 0;
    s[t] = v;
    __syncthreads();
    for (int off = 1; off < NCHUNK; off <<= 1) {
        int x = (t >= off) ? s[t - off] : 0;
        __syncthreads();
        s[t] += x;
        __syncthreads();
    }
    if (d < N_NODES) rowstart[d] = chunkoff[b] + s[t] - v;  // exclusive
}

// ---------------- CSR fill: elist[rowstart[d]+pos] = src | (et<<20) ----------------
__global__ __launch_bounds__(256) void k_fill(const int* __restrict__ src,
                                              const int* __restrict__ dst,
                                              const int* __restrict__ et,
                                              const int* __restrict__ rowstart,
                                              int* __restrict__ cursor,
                                              int* __restrict__ elist) {
    int e = blockIdx.x * 256 + threadIdx.x;
    if (e >= E_EDGES) return;
    int d = dst[e];
    int p = atomicAdd(&cursor[d], 1);
    elist[rowstart[d] + p] = src[e] | (et[e] << 20);
}

// ---------------- GEMM: xw1[M,512](bf16) = emb[M,128](f32->bf16) @ BmT^T ----------------
// 64x64 tile per block, K=128 staged once, 4 waves, 16x16x32 bf16 MFMA
__global__ __launch_bounds__(256) void k_gemm(const float* __restrict__ A,
                                              const unsigned short* __restrict__ BmT,
                                              unsigned short* __restrict__ C,
                                              int M) {
    __shared__ unsigned short As[64 * 136];  // [m][k], pad 8
    __shared__ unsigned short Bs[64 * 136];  // [n][k], pad 8
    int t = threadIdx.x;
    int row0 = blockIdx.x * 64;
    int col0 = blockIdx.y * 64;

    // stage A: 64 rows x 128 k, f32 -> bf16
    #pragma unroll
    for (int j = 0; j < 8; ++j) {
        int idx = t + j * 256;            // 0..2047 float4 units
        int r = idx >> 5;                 // row 0..63
        int c4 = idx & 31;                // float4 col 0..31
        float4 v = make_float4(0.f, 0.f, 0.f, 0.f);
        int grow = row0 + r;
        if (grow < M) v = *(const float4*)(A + (size_t)grow * F_IN + c4 * 4);
        ushort4 o;
        o.x = f2bf(v.x); o.y = f2bf(v.y); o.z = f2bf(v.z); o.w = f2bf(v.w);
        *(ushort4*)(&As[r * 136 + c4 * 4]) = o;
    }
    // stage B: 64 n-rows x 128 k, already bf16
    #pragma unroll
    for (int j = 0; j < 4; ++j) {
        int idx = t + j * 256;            // 0..1023 16B units
        int r = idx >> 4;                 // n-row 0..63
        int u = idx & 15;                 // 8-elem unit
        float4 v = *(const float4*)(BmT + (size_t)(col0 + r) * F_IN + u * 8);
        *(float4*)(&Bs[r * 136 + u * 8]) = v;
    }
    __syncthreads();

    int w = t >> 6;        // wave 0..3 -> rows [16w,16w+16)
    int lane = t & 63;
    int q = lane >> 4;     // quad
    int mr = lane & 15;

    f32x4 acc[4] = {};
    const unsigned short* ap = &As[(w * 16 + mr) * 136 + q * 8];
    #pragma unroll
    for (int kk = 0; kk < 4; ++kk) {
        bf16x8 af = *(const bf16x8*)(ap + kk * 32);
        #pragma unroll
        for (int tt = 0; tt < 4; ++tt) {
            bf16x8 bf = *(const bf16x8*)(&Bs[(tt * 16 + mr) * 136 + q * 8 + kk * 32]);
            acc[tt] = __builtin_amdgcn_mfma_f32_16x16x32_bf16(af, bf, acc[tt], 0, 0, 0);
        }
    }
    #pragma unroll
    for (int tt = 0; tt < 4; ++tt) {
        #pragma unroll
        for (int j = 0; j < 4; ++j) {
            int row = row0 + w * 16 + q * 4 + j;
            if (row < M)
                C[(size_t)row * NOUT + col0 + tt * 16 + mr] = f2bf(acc[tt][j]);
        }
    }
}

// ---------------- layer-1 gather: h[d] = relu(sum_e norm * xw1[src, et]) ----------------
// 16 lanes per node
__global__ __launch_bounds__(256) void k_gather1(const int* __restrict__ rowstart,
                                                 const int* __restrict__ ndeg,
                                                 const int* __restrict__ elist,
                                                 const unsigned short* __restrict__ xw1,
                                                 const float* __restrict__ deg,
                                                 float* __restrict__ h) {
    int t = threadIdx.x;
    int g = t >> 4;
    int c = t & 15;
    int d = blockIdx.x * 16 + g;
    if (d >= N_NODES) return;
    float n0 = 1.0f / fmaxf(deg[(size_t)d * R + c], 1.0f);
    float n1 = 1.0f / fmaxf(deg[(size_t)d * R + 16 + c], 1.0f);
    int start = rowstart[d];
    int cnt = ndeg[d];
    float acc = 0.f;
    for (int i = 0; i < cnt; ++i) {
        int pk = elist[start + i];
        int s = pk & 0xFFFFF;
        int r = pk >> 20;
        float na = __shfl(n0, r & 15, 16);
        float nb = __shfl(n1, r & 15, 16);
        float norm = (r < 16) ? na : nb;
        float x = bf2f(xw1[(size_t)s * NOUT + r * HDIM + c]);
        acc += x * norm;
    }
    h[(size_t)d * HDIM + c] = fmaxf(acc, 0.f);
}

// ---------------- layer-2 gather + fused log_softmax ----------------
// 8 lanes per node; h already relu'd
__global__ __launch_bounds__(256) void k_gather2(const int* __restrict__ rowstart,
                                                 const int* __restrict__ ndeg,
                                                 const int* __restrict__ elist,
                                                 const float* __restrict__ h,
                                                 const float* __restrict__ deg,
                                                 const float* __restrict__ W2,
                                                 float* __restrict__ out) {
    __shared__ float sW2[R * 132];   // [r][k*8+c], padded row stride 132
    int t = threadIdx.x;
    #pragma unroll
    for (int j = 0; j < 16; ++j) {
        int idx = t + j * 256;       // 0..4095
        int r = idx >> 7;
        int rem = idx & 127;
        sW2[r * 132 + rem] = W2[idx];
    }
    __syncthreads();

    int g = t >> 3;
    int c = t & 7;
    int d = blockIdx.x * 32 + g;
    if (d >= N_NODES) return;
    int start = rowstart[d];
    int cnt = ndeg[d];
    float acc = 0.f;
    for (int i = 0; i < cnt; ++i) {
        int pk = elist[start + i];
        int s = pk & 0xFFFFF;
        int r = pk >> 20;
        float norm = 1.0f / fmaxf(deg[(size_t)d * R + r], 1.0f);
        const float* hp = h + (size_t)s * HDIM;
        float4 ha = *(const float4*)(hp);
        float4 hb = *(const float4*)(hp + 4);
        float4 hc = *(const float4*)(hp + 8);
        float4 hd = *(const float4*)(hp + 12);
        const float* wp = &sW2[r * 132 + c];
        float sum = ha.x * wp[0]   + ha.y * wp[8]   + ha.z * wp[16]  + ha.w * wp[24]
                  + hb.x * wp[32]  + hb.y * wp[40]  + hb.z * wp[48]  + hb.w * wp[56]
                  + hc.x * wp[64]  + hc.y * wp[72]  + hc.z * wp[80]  + hc.w * wp[88]
                  + hd.x * wp[96]  + hd.y * wp[104] + hd.z * wp[112] + hd.w * wp[120];
        acc += norm * sum;
    }
    // fused log_softmax across the 8-lane group
    float m = acc;
    #pragma unroll
    for (int mask = 1; mask < 8; mask <<= 1)
        m = fmaxf(m, __shfl_xor(m, mask, 8));
    float ex = expf(acc - m);
    float ssum = ex;
    #pragma unroll
    for (int mask = 1; mask < 8; mask <<= 1)
        ssum += __shfl_xor(ssum, mask, 8);
    out[(size_t)d * CDIM + c] = acc - m - logf(ssum);
}

extern "C" void kernel_launch(void* const* d_in, const int* in_sizes, int n_in,
                              void* d_out, int out_size, void* d_ws, size_t ws_size,
                              hipStream_t stream) {
    const float* emb = (const float*)d_in[0];
    const float* W1  = (const float*)d_in[1];
    const float* W2  = (const float*)d_in[2];
    const int* ei    = (const int*)d_in[3];
    const int* et    = (const int*)d_in[4];
    const int* srcp  = ei;
    const int* dstp  = ei + E_EDGES;

    char* ws = (char*)d_ws;
    size_t off = 0;
    float* deg      = (float*)(ws + off); off += (size_t)N_NODES * R * 4;        // 12.8 MB
    int*   ndeg     = (int*)(ws + off);   off += (size_t)N_NODES * 4;            // 0.4 MB
    int*   rowstart = (int*)(ws + off);   off += (size_t)N_NODES * 4;
    int*   cursor   = (int*)(ws + off);   off += (size_t)N_NODES * 4;
    int*   chunksum = (int*)(ws + off);   off += 1024;
    int*   chunkoff = (int*)(ws + off);   off += 1024;
    int*   elist    = (int*)(ws + off);   off += (size_t)E_EDGES * 4;            // 12.8 MB
    unsigned short* BmT = (unsigned short*)(ws + off); off += (size_t)NOUT * F_IN * 2;
    unsigned short* xw1 = (unsigned short*)(ws + off); off += (size_t)N_NODES * NOUT * 2; // 102.4 MB
    float* h        = (float*)(ws + off); off += (size_t)N_NODES * HDIM * 4;     // 6.4 MB
    float* out      = (float*)d_out;

    hipMemsetAsync(deg, 0, (size_t)N_NODES * R * 4, stream);
    hipMemsetAsync(cursor, 0, (size_t)N_NODES * 4, stream);

    k_deg<<<(E_EDGES + 255) / 256, 256, 0, stream>>>(dstp, et, deg);
    k_prep_w<<<(NOUT * F_IN) / 256, 256, 0, stream>>>(W1, BmT);

    k_scan1<<<NBLK, 256, 0, stream>>>(deg, ndeg, chunksum);
    k_scan2<<<1, 256, 0, stream>>>(chunksum, chunkoff);
    k_scan3<<<NBLK, 512, 0, stream>>>(ndeg, chunkoff, rowstart);
    k_fill<<<(E_EDGES + 255) / 256, 256, 0, stream>>>(srcp, dstp, et, rowstart, cursor, elist);

    dim3 g_gemm((N_NODES + 63) / 64, NOUT / 64);
    k_gemm<<<g_gemm, 256, 0, stream>>>(emb, BmT, xw1, N_NODES);

    k_gather1<<<(N_NODES + 15) / 16, 256, 0, stream>>>(rowstart, ndeg, elist, xw1, deg, h);
    k_gather2<<<(N_NODES + 31) / 32, 256, 0, stream>>>(rowstart, ndeg, elist, h, deg, W2, out);
}

// Round 3
// 545.382 us; speedup vs baseline: 1.5311x; 1.2718x over previous
//
#include <hip/hip_runtime.h>
#include <hip/hip_bf16.h>
#include <math.h>

#define N_NODES 100000
#define R 32
#define E_EDGES 3200000
#define F_IN 128
#define HDIM 16
#define CDIM 8
#define NOUT 512               // R * HDIM
#define NBUCK 391              // ceil(N_NODES / 256)
#define KEYS 8192              // 256 nodes * 32 rels per bucket
#define P1CHUNK 8192
#define P1GRID ((E_EDGES + P1CHUNK - 1) / P1CHUNK)   // 391

typedef __attribute__((ext_vector_type(8))) short bf16x8;
typedef __attribute__((ext_vector_type(4))) float f32x4;

static __device__ __forceinline__ unsigned short f2bf(float f) {
    unsigned int u = __float_as_uint(f);
    unsigned int r = (u + 0x7FFFu + ((u >> 16) & 1u)) >> 16;
    return (unsigned short)r;
}
static __device__ __forceinline__ float bf2f(unsigned short u) {
    return __uint_as_float(((unsigned int)u) << 16);
}

// ---------------- pass 0: bucket histogram (bucket = dst >> 8) ----------------
__global__ __launch_bounds__(512) void k_hist(const int* __restrict__ dst,
                                              int* __restrict__ bucketcount) {
    __shared__ int h[NBUCK];
    int t = threadIdx.x;
    for (int j = t; j < NBUCK; j += 512) h[j] = 0;
    __syncthreads();
    int e0 = blockIdx.x * P1CHUNK;
    int e1 = e0 + P1CHUNK; if (e1 > E_EDGES) e1 = E_EDGES;
    for (int i = e0 + t; i < e1; i += 512)
        atomicAdd(&h[dst[i] >> 8], 1);
    __syncthreads();
    for (int j = t; j < NBUCK; j += 512)
        if (h[j]) atomicAdd(&bucketcount[j], h[j]);
}

// ---------------- bucket scan -> starts + cursors, rowstart sentinel ----------------
__global__ __launch_bounds__(512) void k_scanb(const int* __restrict__ bucketcount,
                                               int* __restrict__ bucketstart,
                                               int* __restrict__ gcursor,
                                               int* __restrict__ rowstart) {
    __shared__ int sb[NBUCK + 1];
    int t = threadIdx.x;
    if (t == 0) {
        int acc = 0;
        for (int b = 0; b < NBUCK; ++b) { int v = bucketcount[b]; sb[b] = acc; acc += v; }
        sb[NBUCK] = acc;
        rowstart[N_NODES] = acc;   // == E_EDGES
    }
    __syncthreads();
    for (int j = t; j <= NBUCK; j += 512) bucketstart[j] = sb[j];
    for (int j = t; j < NBUCK; j += 512) gcursor[j] = sb[j];
}

// ---------------- pass 1: scatter edges into dst-buckets (coalesced runs) ----------------
// packed: dl(8b)<<22 | et(5b)<<17 | src(17b)
__global__ __launch_bounds__(512) void k_bucket(const int* __restrict__ src,
                                                const int* __restrict__ dst,
                                                const int* __restrict__ et,
                                                int* __restrict__ gcursor,
                                                unsigned int* __restrict__ ebuf) {
    __shared__ int hist[NBUCK];
    __shared__ int rank[NBUCK];
    __shared__ int base[NBUCK];
    int t = threadIdx.x;
    for (int j = t; j < NBUCK; j += 512) { hist[j] = 0; rank[j] = 0; }
    __syncthreads();
    int e0 = blockIdx.x * P1CHUNK;
    int e1 = e0 + P1CHUNK; if (e1 > E_EDGES) e1 = E_EDGES;
    for (int i = e0 + t; i < e1; i += 512)
        atomicAdd(&hist[dst[i] >> 8], 1);
    __syncthreads();
    for (int j = t; j < NBUCK; j += 512)
        base[j] = hist[j] ? atomicAdd(&gcursor[j], hist[j]) : 0;
    __syncthreads();
    for (int i = e0 + t; i < e1; i += 512) {
        int d = dst[i];
        int bk = d >> 8;
        unsigned pk = ((unsigned)(d & 255) << 22) | ((unsigned)et[i] << 17)
                    | (unsigned)src[i];
        int lr = atomicAdd(&rank[bk], 1);
        ebuf[base[bk] + lr] = pk;
    }
}

// ---------------- pass 2: per-bucket counting sort by (dl, et) + rowstart ----------------
__global__ __launch_bounds__(1024) void k_sortb(const unsigned int* __restrict__ ebuf,
                                                const int* __restrict__ bucketstart,
                                                int* __restrict__ rowstart,
                                                unsigned int* __restrict__ elist) {
    __shared__ int cnt[KEYS];     // 32 KB
    __shared__ int ssum[1024];
    int t = threadIdx.x, b = blockIdx.x;
    int e0 = bucketstart[b], e1 = bucketstart[b + 1];
    #pragma unroll
    for (int j = 0; j < KEYS / 1024; ++j) cnt[t + j * 1024] = 0;
    __syncthreads();
    for (int i = e0 + t; i < e1; i += 1024)
        atomicAdd(&cnt[ebuf[i] >> 17], 1);    // key = dl*32 + et
    __syncthreads();
    int kbase = t * (KEYS / 1024);
    int s = 0;
    #pragma unroll
    for (int j = 0; j < KEYS / 1024; ++j) s += cnt[kbase + j];
    ssum[t] = s;
    __syncthreads();
    for (int off = 1; off < 1024; off <<= 1) {
        int v = (t >= off) ? ssum[t - off] : 0;
        __syncthreads();
        ssum[t] += v;
        __syncthreads();
    }
    int run = ssum[t] - s;   // exclusive base for this thread's keys
    #pragma unroll
    for (int j = 0; j < KEYS / 1024; ++j) {
        int v = cnt[kbase + j]; cnt[kbase + j] = run; run += v;
    }
    __syncthreads();
    if (t < 256) {
        int d = b * 256 + t;
        if (d < N_NODES) rowstart[d] = e0 + cnt[t * 32];
    }
    __syncthreads();
    for (int i = e0 + t; i < e1; i += 1024) {
        unsigned pk = ebuf[i];
        int key = pk >> 17;
        int pos = atomicAdd(&cnt[key], 1);
        // final pack: src(17b) | et(5b)<<17
        elist[e0 + pos] = (pk & 0x1FFFFu) | ((unsigned)(key & 31) << 17);
    }
}

// ---------------- repack W1 [R,128,16] -> BmT bf16 [512][128] ----------------
__global__ __launch_bounds__(256) void k_prep_w(const float* __restrict__ W1,
                                                unsigned short* __restrict__ BmT) {
    int i = blockIdx.x * 256 + threadIdx.x;   // i = n*128 + f
    if (i >= NOUT * F_IN) return;
    int n = i >> 7;
    int f = i & 127;
    int r = n >> 4;
    int o = n & 15;
    BmT[i] = f2bf(W1[r * (F_IN * HDIM) + f * HDIM + o]);
}

// ---------------- GEMM: xw1[M,512](bf16) = emb[M,128] @ BmT^T (MFMA) ----------------
__global__ __launch_bounds__(256) void k_gemm(const float* __restrict__ A,
                                              const unsigned short* __restrict__ BmT,
                                              unsigned short* __restrict__ C,
                                              int M) {
    __shared__ unsigned short As[64 * 136];
    __shared__ unsigned short Bs[64 * 136];
    int t = threadIdx.x;
    int row0 = blockIdx.x * 64;
    int col0 = blockIdx.y * 64;

    #pragma unroll
    for (int j = 0; j < 8; ++j) {
        int idx = t + j * 256;
        int r = idx >> 5;
        int c4 = idx & 31;
        float4 v = make_float4(0.f, 0.f, 0.f, 0.f);
        int grow = row0 + r;
        if (grow < M) v = *(const float4*)(A + (size_t)grow * F_IN + c4 * 4);
        ushort4 o;
        o.x = f2bf(v.x); o.y = f2bf(v.y); o.z = f2bf(v.z); o.w = f2bf(v.w);
        *(ushort4*)(&As[r * 136 + c4 * 4]) = o;
    }
    #pragma unroll
    for (int j = 0; j < 4; ++j) {
        int idx = t + j * 256;
        int r = idx >> 4;
        int u = idx & 15;
        float4 v = *(const float4*)(BmT + (size_t)(col0 + r) * F_IN + u * 8);
        *(float4*)(&Bs[r * 136 + u * 8]) = v;
    }
    __syncthreads();

    int w = t >> 6;
    int lane = t & 63;
    int q = lane >> 4;
    int mr = lane & 15;

    f32x4 acc[4] = {};
    const unsigned short* ap = &As[(w * 16 + mr) * 136 + q * 8];
    #pragma unroll
    for (int kk = 0; kk < 4; ++kk) {
        bf16x8 af = *(const bf16x8*)(ap + kk * 32);
        #pragma unroll
        for (int tt = 0; tt < 4; ++tt) {
            bf16x8 bf = *(const bf16x8*)(&Bs[(tt * 16 + mr) * 136 + q * 8 + kk * 32]);
            acc[tt] = __builtin_amdgcn_mfma_f32_16x16x32_bf16(af, bf, acc[tt], 0, 0, 0);
        }
    }
    #pragma unroll
    for (int tt = 0; tt < 4; ++tt) {
        #pragma unroll
        for (int j = 0; j < 4; ++j) {
            int row = row0 + w * 16 + q * 4 + j;
            if (row < M)
                C[(size_t)row * NOUT + col0 + tt * 16 + mr] = f2bf(acc[tt][j]);
        }
    }
}

// ---------------- layer-1 gather, norm from run length: 16 lanes/node ----------------
__global__ __launch_bounds__(256) void k_gather1(const int* __restrict__ rowstart,
                                                 const unsigned int* __restrict__ elist,
                                                 const unsigned short* __restrict__ xw1,
                                                 float* __restrict__ h) {
    int t = threadIdx.x;
    int g = t >> 4;
    int c = t & 15;
    int d = blockIdx.x * 16 + g;
    if (d >= N_NODES) return;
    int i = rowstart[d], end = rowstart[d + 1];
    float acc = 0.f;
    while (i < end) {
        unsigned pk = elist[i];
        int r = pk >> 17;
        float racc = 0.f;
        int len = 0;
        for (;;) {
            int s = pk & 0x1FFFF;
            racc += bf2f(xw1[(size_t)s * NOUT + r * HDIM + c]);
            ++i; ++len;
            if (i >= end) break;
            pk = elist[i];
            if ((int)(pk >> 17) != r) break;
        }
        acc += racc * (1.0f / (float)len);
    }
    h[(size_t)d * HDIM + c] = fmaxf(acc, 0.f);
}

// ---------------- layer-2 gather + fused log_softmax: 8 lanes/node ----------------
__global__ __launch_bounds__(256) void k_gather2(const int* __restrict__ rowstart,
                                                 const unsigned int* __restrict__ elist,
                                                 const float* __restrict__ h,
                                                 const float* __restrict__ W2,
                                                 float* __restrict__ out) {
    __shared__ float sW2[R * 132];
    int t = threadIdx.x;
    #pragma unroll
    for (int j = 0; j < 16; ++j) {
        int idx = t + j * 256;
        int r = idx >> 7;
        int rem = idx & 127;
        sW2[r * 132 + rem] = W2[idx];
    }
    __syncthreads();

    int g = t >> 3;
    int c = t & 7;
    int d = blockIdx.x * 32 + g;
    if (d >= N_NODES) return;
    int i = rowstart[d], end = rowstart[d + 1];
    float acc = 0.f;
    while (i < end) {
        unsigned pk = elist[i];
        int r = pk >> 17;
        const float* wp = &sW2[r * 132 + c];
        float racc = 0.f;
        int len = 0;
        for (;;) {
            int s = pk & 0x1FFFF;
            const float* hp = h + (size_t)s * HDIM;
            float4 ha = *(const float4*)(hp);
            float4 hb = *(const float4*)(hp + 4);
            float4 hc = *(const float4*)(hp + 8);
            float4 hd = *(const float4*)(hp + 12);
            racc += ha.x * wp[0]   + ha.y * wp[8]   + ha.z * wp[16]  + ha.w * wp[24]
                  + hb.x * wp[32]  + hb.y * wp[40]  + hb.z * wp[48]  + hb.w * wp[56]
                  + hc.x * wp[64]  + hc.y * wp[72]  + hc.z * wp[80]  + hc.w * wp[88]
                  + hd.x * wp[96]  + hd.y * wp[104] + hd.z * wp[112] + hd.w * wp[120];
            ++i; ++len;
            if (i >= end) break;
            pk = elist[i];
            if ((int)(pk >> 17) != r) break;
        }
        acc += racc * (1.0f / (float)len);
    }
    float m = acc;
    #pragma unroll
    for (int mask = 1; mask < 8; mask <<= 1)
        m = fmaxf(m, __shfl_xor(m, mask, 8));
    float ex = expf(acc - m);
    float ssumv = ex;
    #pragma unroll
    for (int mask = 1; mask < 8; mask <<= 1)
        ssumv += __shfl_xor(ssumv, mask, 8);
    out[(size_t)d * CDIM + c] = acc - m - logf(ssumv);
}

extern "C" void kernel_launch(void* const* d_in, const int* in_sizes, int n_in,
                              void* d_out, int out_size, void* d_ws, size_t ws_size,
                              hipStream_t stream) {
    const float* emb = (const float*)d_in[0];
    const float* W1  = (const float*)d_in[1];
    const float* W2  = (const float*)d_in[2];
    const int* ei    = (const int*)d_in[3];
    const int* et    = (const int*)d_in[4];
    const int* srcp  = ei;
    const int* dstp  = ei + E_EDGES;

    char* ws = (char*)d_ws;
    size_t off = 0;
    int* bucketcount = (int*)(ws + off); off += 512 * 4;
    int* bucketstart = (int*)(ws + off); off += 512 * 4;
    int* gcursor     = (int*)(ws + off); off += 512 * 4;
    int* rowstart    = (int*)(ws + off); off += ((size_t)N_NODES + 8) * 4;
    unsigned int* ebuf  = (unsigned int*)(ws + off); off += (size_t)E_EDGES * 4;
    unsigned int* elist = (unsigned int*)(ws + off); off += (size_t)E_EDGES * 4;
    unsigned short* BmT = (unsigned short*)(ws + off); off += (size_t)NOUT * F_IN * 2;
    unsigned short* xw1 = (unsigned short*)(ws + off); off += (size_t)N_NODES * NOUT * 2;
    float* h         = (float*)(ws + off); off += (size_t)N_NODES * HDIM * 4;
    float* out       = (float*)d_out;

    hipMemsetAsync(bucketcount, 0, NBUCK * 4, stream);

    k_hist<<<P1GRID, 512, 0, stream>>>(dstp, bucketcount);
    k_scanb<<<1, 512, 0, stream>>>(bucketcount, bucketstart, gcursor, rowstart);
    k_bucket<<<P1GRID, 512, 0, stream>>>(srcp, dstp, et, gcursor, ebuf);

    k_prep_w<<<(NOUT * F_IN) / 256, 256, 0, stream>>>(W1, BmT);
    dim3 g_gemm((N_NODES + 63) / 64, NOUT / 64);
    k_gemm<<<g_gemm, 256, 0, stream>>>(emb, BmT, xw1, N_NODES);

    k_sortb<<<NBUCK, 1024, 0, stream>>>(ebuf, bucketstart, rowstart, elist);

    k_gather1<<<(N_NODES + 15) / 16, 256, 0, stream>>>(rowstart, elist, xw1, h);
    k_gather2<<<(N_NODES + 31) / 32, 256, 0, stream>>>(rowstart, elist, h, W2, out);
}

// Round 4
// 442.219 us; speedup vs baseline: 1.8882x; 1.2333x over previous
//
#include <hip/hip_runtime.h>
#include <hip/hip_bf16.h>
#include <math.h>

#define N_NODES 100000
#define R 32
#define E_EDGES 3200000
#define F_IN 128
#define HDIM 16
#define CDIM 8
#define NOUT 512               // R * HDIM
#define M_PAD 100032           // 1563 * 64
#define NBUCK 391              // ceil(N_NODES / 256)
#define KEYS 8192              // 256 nodes * 32 rels per bucket
#define P1CHUNK 8192
#define P1GRID ((E_EDGES + P1CHUNK - 1) / P1CHUNK)   // 391
#define W2S 516                // padded per-class stride (floats)

typedef __attribute__((ext_vector_type(8))) short bf16x8;
typedef __attribute__((ext_vector_type(4))) float f32x4;

static __device__ __forceinline__ unsigned short f2bf(float f) {
    unsigned int u = __float_as_uint(f);
    unsigned int r = (u + 0x7FFFu + ((u >> 16) & 1u)) >> 16;
    return (unsigned short)r;
}
static __device__ __forceinline__ float bflo(float packed) {
    return __uint_as_float(__float_as_uint(packed) << 16);
}
static __device__ __forceinline__ float bfhi(float packed) {
    return __uint_as_float(__float_as_uint(packed) & 0xFFFF0000u);
}

// ---------------- pass 0: bucket histogram (bucket = dst >> 8) ----------------
__global__ __launch_bounds__(512) void k_hist(const int* __restrict__ dst,
                                              int* __restrict__ bucketcount) {
    __shared__ int h[NBUCK];
    int t = threadIdx.x;
    for (int j = t; j < NBUCK; j += 512) h[j] = 0;
    __syncthreads();
    int e0 = blockIdx.x * P1CHUNK;
    int e1 = e0 + P1CHUNK; if (e1 > E_EDGES) e1 = E_EDGES;
    for (int i = e0 + t; i < e1; i += 512)
        atomicAdd(&h[dst[i] >> 8], 1);
    __syncthreads();
    for (int j = t; j < NBUCK; j += 512)
        if (h[j]) atomicAdd(&bucketcount[j], h[j]);
}

// ---------------- bucket scan -> starts + cursors, rowstart sentinel ----------------
__global__ __launch_bounds__(512) void k_scanb(const int* __restrict__ bucketcount,
                                               int* __restrict__ bucketstart,
                                               int* __restrict__ gcursor,
                                               int* __restrict__ rowstart) {
    __shared__ int sb[NBUCK + 1];
    int t = threadIdx.x;
    if (t == 0) {
        int acc = 0;
        for (int b = 0; b < NBUCK; ++b) { int v = bucketcount[b]; sb[b] = acc; acc += v; }
        sb[NBUCK] = acc;
        rowstart[N_NODES] = acc;   // == E_EDGES
    }
    __syncthreads();
    for (int j = t; j <= NBUCK; j += 512) bucketstart[j] = sb[j];
    for (int j = t; j < NBUCK; j += 512) gcursor[j] = sb[j];
}

// ---------------- pass 1: scatter edges into dst-buckets ----------------
// packed: dl(8b)<<22 | et(5b)<<17 | src(17b)
__global__ __launch_bounds__(512) void k_bucket(const int* __restrict__ src,
                                                const int* __restrict__ dst,
                                                const int* __restrict__ et,
                                                int* __restrict__ gcursor,
                                                unsigned int* __restrict__ ebuf) {
    __shared__ int hist[NBUCK];
    __shared__ int rank[NBUCK];
    __shared__ int base[NBUCK];
    int t = threadIdx.x;
    for (int j = t; j < NBUCK; j += 512) { hist[j] = 0; rank[j] = 0; }
    __syncthreads();
    int e0 = blockIdx.x * P1CHUNK;
    int e1 = e0 + P1CHUNK; if (e1 > E_EDGES) e1 = E_EDGES;
    for (int i = e0 + t; i < e1; i += 512)
        atomicAdd(&hist[dst[i] >> 8], 1);
    __syncthreads();
    for (int j = t; j < NBUCK; j += 512)
        base[j] = hist[j] ? atomicAdd(&gcursor[j], hist[j]) : 0;
    __syncthreads();
    for (int i = e0 + t; i < e1; i += 512) {
        int d = dst[i];
        int bk = d >> 8;
        unsigned pk = ((unsigned)(d & 255) << 22) | ((unsigned)et[i] << 17)
                    | (unsigned)src[i];
        int lr = atomicAdd(&rank[bk], 1);
        ebuf[base[bk] + lr] = pk;
    }
}

// ---------------- pass 2: per-bucket counting sort; len packed into elist ----------------
// final elist entry: len(10b)<<22 | et(5b)<<17 | src(17b)
__global__ __launch_bounds__(1024) void k_sortb(const unsigned int* __restrict__ ebuf,
                                                const int* __restrict__ bucketstart,
                                                int* __restrict__ rowstart,
                                                unsigned int* __restrict__ elist) {
    __shared__ unsigned int cnt[KEYS];     // 32 KB; packed (len<<20)|offset
    __shared__ int ssum[1024];
    int t = threadIdx.x, b = blockIdx.x;
    int e0 = bucketstart[b], e1 = bucketstart[b + 1];
    #pragma unroll
    for (int j = 0; j < KEYS / 1024; ++j) cnt[t + j * 1024] = 0;
    __syncthreads();
    for (int i = e0 + t; i < e1; i += 1024)
        atomicAdd(&cnt[ebuf[i] >> 17], 1u);    // key = dl*32 + et
    __syncthreads();
    int kbase = t * (KEYS / 1024);
    int s = 0;
    #pragma unroll
    for (int j = 0; j < KEYS / 1024; ++j) s += (int)cnt[kbase + j];
    ssum[t] = s;
    __syncthreads();
    for (int off = 1; off < 1024; off <<= 1) {
        int v = (t >= off) ? ssum[t - off] : 0;
        __syncthreads();
        ssum[t] += v;
        __syncthreads();
    }
    int run = ssum[t] - s;
    #pragma unroll
    for (int j = 0; j < KEYS / 1024; ++j) {
        unsigned v = cnt[kbase + j];
        unsigned lc = v > 1023u ? 1023u : v;
        cnt[kbase + j] = (unsigned)run | (lc << 20);
        run += (int)v;
    }
    __syncthreads();
    if (t < 256) {
        int d = b * 256 + t;
        if (d < N_NODES) rowstart[d] = e0 + (int)(cnt[t * 32] & 0xFFFFFu);
    }
    __syncthreads();
    for (int i = e0 + t; i < e1; i += 1024) {
        unsigned pk = ebuf[i];
        int key = pk >> 17;
        unsigned vv = atomicAdd(&cnt[key], 1u);
        int pos = (int)(vv & 0xFFFFFu);
        unsigned len = (vv >> 20) & 1023u;
        elist[e0 + pos] = (pk & 0x3FFFFFu) | (len << 22);
    }
}

// ---------------- emb f32 -> bf16, rows padded to M_PAD with zeros ----------------
__global__ __launch_bounds__(256) void k_cvt(const float* __restrict__ emb,
                                             unsigned short* __restrict__ out) {
    int g = blockIdx.x * 256 + threadIdx.x;       // unit of 4 elems
    size_t base = (size_t)g * 4;
    if (base >= (size_t)M_PAD * F_IN) return;
    int row = (int)(base >> 7);
    ushort4 o;
    if (row < N_NODES) {
        float4 a = *(const float4*)(emb + base);
        o.x = f2bf(a.x); o.y = f2bf(a.y); o.z = f2bf(a.z); o.w = f2bf(a.w);
    } else {
        o.x = o.y = o.z = o.w = 0;
    }
    *(ushort4*)(out + base) = o;
}

// ---------------- repack W1 [R,128,16] -> BmT bf16 [512][128] ----------------
__global__ __launch_bounds__(256) void k_prep_w(const float* __restrict__ W1,
                                                unsigned short* __restrict__ BmT) {
    int i = blockIdx.x * 256 + threadIdx.x;   // i = n*128 + f
    if (i >= NOUT * F_IN) return;
    int n = i >> 7;
    int f = i & 127;
    int r = n >> 4;
    int o = n & 15;
    BmT[i] = f2bf(W1[r * (F_IN * HDIM) + f * HDIM + o]);
}

// ---------------- GEMM: xw1[M_PAD,512](bf16) = Abf[M_PAD,128] @ BmT^T (MFMA) ----------------
__global__ __launch_bounds__(256) void k_gemm(const unsigned short* __restrict__ Abf,
                                              const unsigned short* __restrict__ BmT,
                                              unsigned short* __restrict__ C) {
    __shared__ unsigned short As[64 * 136];
    __shared__ unsigned short Bs[64 * 136];
    int t = threadIdx.x;
    int row0 = blockIdx.x * 64;
    int col0 = blockIdx.y * 64;

    #pragma unroll
    for (int j = 0; j < 4; ++j) {
        int idx = t + j * 256;            // 0..1023 8-elem units
        int r = idx >> 4;
        int u = idx & 15;
        float4 v = *(const float4*)(Abf + (size_t)(row0 + r) * F_IN + u * 8);
        *(float4*)(&As[r * 136 + u * 8]) = v;
    }
    #pragma unroll
    for (int j = 0; j < 4; ++j) {
        int idx = t + j * 256;
        int r = idx >> 4;
        int u = idx & 15;
        float4 v = *(const float4*)(BmT + (size_t)(col0 + r) * F_IN + u * 8);
        *(float4*)(&Bs[r * 136 + u * 8]) = v;
    }
    __syncthreads();

    int w = t >> 6;
    int lane = t & 63;
    int q = lane >> 4;
    int mr = lane & 15;

    f32x4 acc[4] = {};
    const unsigned short* ap = &As[(w * 16 + mr) * 136 + q * 8];
    #pragma unroll
    for (int kk = 0; kk < 4; ++kk) {
        bf16x8 af = *(const bf16x8*)(ap + kk * 32);
        #pragma unroll
        for (int tt = 0; tt < 4; ++tt) {
            bf16x8 bf = *(const bf16x8*)(&Bs[(tt * 16 + mr) * 136 + q * 8 + kk * 32]);
            acc[tt] = __builtin_amdgcn_mfma_f32_16x16x32_bf16(af, bf, acc[tt], 0, 0, 0);
        }
    }
    #pragma unroll
    for (int tt = 0; tt < 4; ++tt) {
        #pragma unroll
        for (int j = 0; j < 4; ++j) {
            int row = row0 + w * 16 + q * 4 + j;
            C[(size_t)row * NOUT + col0 + tt * 16 + mr] = f2bf(acc[tt][j]);
        }
    }
}

// ---------------- layer-1 gather: flat loop, 8 lanes/node, h bf16 out ----------------
__global__ __launch_bounds__(256) void k_gather1(const int* __restrict__ rowstart,
                                                 const unsigned int* __restrict__ elist,
                                                 const unsigned short* __restrict__ xw1,
                                                 unsigned short* __restrict__ h) {
    __shared__ float nlut[1024];
    int t = threadIdx.x;
    for (int j = t; j < 1024; j += 256) nlut[j] = 1.0f / (float)(j ? j : 1);
    __syncthreads();
    int g = t >> 3;
    int c = t & 7;
    int d = blockIdx.x * 32 + g;
    if (d >= N_NODES) return;
    int i = rowstart[d], end = rowstart[d + 1];
    float a0 = 0.f, a1 = 0.f;
    for (; i < end; ++i) {
        unsigned pk = elist[i];
        int s = pk & 0x1FFFF;
        int r = (pk >> 17) & 31;
        float nm = nlut[pk >> 22];
        unsigned x = *(const unsigned*)(xw1 + (size_t)s * NOUT + r * HDIM + c * 2);
        a0 += __uint_as_float(x << 16) * nm;
        a1 += __uint_as_float(x & 0xFFFF0000u) * nm;
    }
    ushort2 o;
    o.x = f2bf(fmaxf(a0, 0.f));
    o.y = f2bf(fmaxf(a1, 0.f));
    *(ushort2*)(h + (size_t)d * HDIM + c * 2) = o;
}

// ---------------- layer-2 gather + fused log_softmax: 8 lanes/node ----------------
__global__ __launch_bounds__(256) void k_gather2(const int* __restrict__ rowstart,
                                                 const unsigned int* __restrict__ elist,
                                                 const unsigned short* __restrict__ h,
                                                 const float* __restrict__ W2,
                                                 float* __restrict__ out) {
    __shared__ float sW2t[CDIM * W2S];   // [c][r*16+k], stride 516
    __shared__ float nlut[1024];
    int t = threadIdx.x;
    for (int j = t; j < 1024; j += 256) nlut[j] = 1.0f / (float)(j ? j : 1);
    #pragma unroll
    for (int j = 0; j < 16; ++j) {
        int idx = t + j * 256;           // 0..4095
        int c = idx >> 9;
        int rem = idx & 511;
        int r = rem >> 4;
        int k = rem & 15;
        sW2t[c * W2S + rem] = W2[r * (HDIM * CDIM) + k * CDIM + c];
    }
    __syncthreads();

    int g = t >> 3;
    int c = t & 7;
    int d = blockIdx.x * 32 + g;
    if (d >= N_NODES) return;
    const float* wc = &sW2t[c * W2S];
    int i = rowstart[d], end = rowstart[d + 1];
    float acc = 0.f;
    for (; i < end; ++i) {
        unsigned pk = elist[i];
        int s = pk & 0x1FFFF;
        int r = (pk >> 17) & 31;
        float nm = nlut[pk >> 22];
        const float4* hp = (const float4*)(h + (size_t)s * HDIM);   // 32 B row
        float4 u0 = hp[0];
        float4 u1 = hp[1];
        const float* wp = wc + r * 16;
        float4 w0 = *(const float4*)(wp);
        float4 w1 = *(const float4*)(wp + 4);
        float4 w2 = *(const float4*)(wp + 8);
        float4 w3 = *(const float4*)(wp + 12);
        float sum = bflo(u0.x) * w0.x + bfhi(u0.x) * w0.y
                  + bflo(u0.y) * w0.z + bfhi(u0.y) * w0.w
                  + bflo(u0.z) * w1.x + bfhi(u0.z) * w1.y
                  + bflo(u0.w) * w1.z + bfhi(u0.w) * w1.w
                  + bflo(u1.x) * w2.x + bfhi(u1.x) * w2.y
                  + bflo(u1.y) * w2.z + bfhi(u1.y) * w2.w
                  + bflo(u1.z) * w3.x + bfhi(u1.z) * w3.y
                  + bflo(u1.w) * w3.z + bfhi(u1.w) * w3.w;
        acc += nm * sum;
    }
    float m = acc;
    #pragma unroll
    for (int mask = 1; mask < 8; mask <<= 1)
        m = fmaxf(m, __shfl_xor(m, mask, 8));
    float ex = expf(acc - m);
    float ssumv = ex;
    #pragma unroll
    for (int mask = 1; mask < 8; mask <<= 1)
        ssumv += __shfl_xor(ssumv, mask, 8);
    out[(size_t)d * CDIM + c] = acc - m - logf(ssumv);
}

extern "C" void kernel_launch(void* const* d_in, const int* in_sizes, int n_in,
                              void* d_out, int out_size, void* d_ws, size_t ws_size,
                              hipStream_t stream) {
    const float* emb = (const float*)d_in[0];
    const float* W1  = (const float*)d_in[1];
    const float* W2  = (const float*)d_in[2];
    const int* ei    = (const int*)d_in[3];
    const int* et    = (const int*)d_in[4];
    const int* srcp  = ei;
    const int* dstp  = ei + E_EDGES;

    char* ws = (char*)d_ws;
    size_t off = 0;
    int* bucketcount = (int*)(ws + off); off += 512 * 4;
    int* bucketstart = (int*)(ws + off); off += 512 * 4;
    int* gcursor     = (int*)(ws + off); off += 512 * 4;
    int* rowstart    = (int*)(ws + off); off += ((size_t)N_NODES + 8) * 4;
    unsigned int* ebuf  = (unsigned int*)(ws + off); off += (size_t)E_EDGES * 4;
    unsigned int* elist = (unsigned int*)(ws + off); off += (size_t)E_EDGES * 4;
    unsigned short* BmT  = (unsigned short*)(ws + off); off += (size_t)NOUT * F_IN * 2;
    unsigned short* ebf  = (unsigned short*)(ws + off); off += (size_t)M_PAD * F_IN * 2;
    unsigned short* xw1  = (unsigned short*)(ws + off); off += (size_t)M_PAD * NOUT * 2;
    unsigned short* h    = (unsigned short*)(ws + off); off += (size_t)N_NODES * HDIM * 2;
    float* out = (float*)d_out;

    hipMemsetAsync(bucketcount, 0, NBUCK * 4, stream);

    k_hist<<<P1GRID, 512, 0, stream>>>(dstp, bucketcount);
    k_scanb<<<1, 512, 0, stream>>>(bucketcount, bucketstart, gcursor, rowstart);
    k_bucket<<<P1GRID, 512, 0, stream>>>(srcp, dstp, et, gcursor, ebuf);
    k_sortb<<<NBUCK, 1024, 0, stream>>>(ebuf, bucketstart, rowstart, elist);

    k_cvt<<<((M_PAD * F_IN / 4) + 255) / 256, 256, 0, stream>>>(emb, ebf);
    k_prep_w<<<(NOUT * F_IN) / 256, 256, 0, stream>>>(W1, BmT);
    dim3 g_gemm(M_PAD / 64, NOUT / 64);
    k_gemm<<<g_gemm, 256, 0, stream>>>(ebf, BmT, xw1);

    k_gather1<<<(N_NODES + 31) / 32, 256, 0, stream>>>(rowstart, elist, xw1, h);
    k_gather2<<<(N_NODES + 31) / 32, 256, 0, stream>>>(rowstart, elist, h, W2, out);
}

// Round 5
// 347.401 us; speedup vs baseline: 2.4036x; 1.2729x over previous
//
#include <hip/hip_runtime.h>
#include <hip/hip_bf16.h>
#include <math.h>

#define N_NODES 100000
#define R 32
#define E_EDGES 3200000
#define F_IN 128
#define HDIM 16
#define CDIM 8
#define NOUT 512               // R * HDIM
#define M_PAD 100032           // 1563 * 64
#define NBUCK 391              // ceil(N_NODES / 256)
#define KEYS 8192              // 256 nodes * 32 rels per bucket
#define P1CHUNK 8192
#define P1GRID ((E_EDGES + P1CHUNK - 1) / P1CHUNK)   // 391

typedef __attribute__((ext_vector_type(8))) short bf16x8;
typedef __attribute__((ext_vector_type(4))) float f32x4;
typedef __attribute__((ext_vector_type(2))) _Float16 f16x2;

static __device__ __forceinline__ unsigned short f2bf(float f) {
    unsigned int u = __float_as_uint(f);
    unsigned int r = (u + 0x7FFFu + ((u >> 16) & 1u)) >> 16;
    return (unsigned short)r;
}
static __device__ __forceinline__ f16x2 asf16x2(float f) {
    union { float f; f16x2 h; } u; u.f = f; return u.h;
}

#if __has_builtin(__builtin_amdgcn_fdot2)
static __device__ __forceinline__ float FDOT2(f16x2 a, f16x2 b, float c) {
    return __builtin_amdgcn_fdot2(a, b, c, false);
}
#else
static __device__ __forceinline__ float FDOT2(f16x2 a, f16x2 b, float c) {
    return c + (float)a.x * (float)b.x + (float)a.y * (float)b.y;
}
#endif

// ---------------- pass 0: bucket histogram (bucket = dst >> 8) ----------------
__global__ __launch_bounds__(512) void k_hist(const int* __restrict__ dst,
                                              int* __restrict__ bucketcount) {
    __shared__ int h[NBUCK];
    int t = threadIdx.x;
    for (int j = t; j < NBUCK; j += 512) h[j] = 0;
    __syncthreads();
    int e0 = blockIdx.x * P1CHUNK;
    int e1 = e0 + P1CHUNK; if (e1 > E_EDGES) e1 = E_EDGES;
    int n4 = (e1 - e0) >> 2;                  // all chunks divisible by 4
    const int4* d4 = (const int4*)(dst + e0);
    for (int i = t; i < n4; i += 512) {
        int4 v = d4[i];
        atomicAdd(&h[v.x >> 8], 1);
        atomicAdd(&h[v.y >> 8], 1);
        atomicAdd(&h[v.z >> 8], 1);
        atomicAdd(&h[v.w >> 8], 1);
    }
    __syncthreads();
    for (int j = t; j < NBUCK; j += 512)
        if (h[j]) atomicAdd(&bucketcount[j], h[j]);
}

// ---------------- bucket scan -> starts + cursors, rowstart sentinel ----------------
__global__ __launch_bounds__(512) void k_scanb(const int* __restrict__ bucketcount,
                                               int* __restrict__ bucketstart,
                                               int* __restrict__ gcursor,
                                               int* __restrict__ rowstart) {
    __shared__ int sb[NBUCK + 1];
    int t = threadIdx.x;
    if (t == 0) {
        int acc = 0;
        for (int b = 0; b < NBUCK; ++b) { int v = bucketcount[b]; sb[b] = acc; acc += v; }
        sb[NBUCK] = acc;
        rowstart[N_NODES] = acc;   // == E_EDGES
    }
    __syncthreads();
    for (int j = t; j <= NBUCK; j += 512) bucketstart[j] = sb[j];
    for (int j = t; j < NBUCK; j += 512) gcursor[j] = sb[j];
}

// ---------------- pass 1: scatter edges into dst-buckets ----------------
// packed: dl(8b)<<22 | et(5b)<<17 | src(17b)
__global__ __launch_bounds__(512) void k_bucket(const int* __restrict__ src,
                                                const int* __restrict__ dst,
                                                const int* __restrict__ et,
                                                int* __restrict__ gcursor,
                                                unsigned int* __restrict__ ebuf) {
    __shared__ int hist[NBUCK];
    __shared__ int rank[NBUCK];
    __shared__ int base[NBUCK];
    int t = threadIdx.x;
    for (int j = t; j < NBUCK; j += 512) { hist[j] = 0; rank[j] = 0; }
    __syncthreads();
    int e0 = blockIdx.x * P1CHUNK;
    int e1 = e0 + P1CHUNK; if (e1 > E_EDGES) e1 = E_EDGES;
    int n4 = (e1 - e0) >> 2;
    const int4* d4 = (const int4*)(dst + e0);
    const int4* s4 = (const int4*)(src + e0);
    const int4* t4 = (const int4*)(et + e0);
    for (int i = t; i < n4; i += 512) {
        int4 v = d4[i];
        atomicAdd(&hist[v.x >> 8], 1);
        atomicAdd(&hist[v.y >> 8], 1);
        atomicAdd(&hist[v.z >> 8], 1);
        atomicAdd(&hist[v.w >> 8], 1);
    }
    __syncthreads();
    for (int j = t; j < NBUCK; j += 512)
        base[j] = hist[j] ? atomicAdd(&gcursor[j], hist[j]) : 0;
    __syncthreads();
    for (int i = t; i < n4; i += 512) {
        int4 dv = d4[i];
        int4 sv = s4[i];
        int4 tv = t4[i];
        int ds[4] = {dv.x, dv.y, dv.z, dv.w};
        int ss[4] = {sv.x, sv.y, sv.z, sv.w};
        int ts[4] = {tv.x, tv.y, tv.z, tv.w};
        #pragma unroll
        for (int u = 0; u < 4; ++u) {
            int d = ds[u];
            int bk = d >> 8;
            unsigned pk = ((unsigned)(d & 255) << 22) | ((unsigned)ts[u] << 17)
                        | (unsigned)ss[u];
            int lr = atomicAdd(&rank[bk], 1);
            ebuf[base[bk] + lr] = pk;
        }
    }
}

// ---------------- pass 2: per-bucket counting sort; len packed into elist ----------------
// final elist entry: len(10b)<<22 | et(5b)<<17 | src(17b)
__global__ __launch_bounds__(1024) void k_sortb(const unsigned int* __restrict__ ebuf,
                                                const int* __restrict__ bucketstart,
                                                int* __restrict__ rowstart,
                                                unsigned int* __restrict__ elist) {
    __shared__ unsigned int cnt[KEYS];     // 32 KB; packed (len<<20)|offset
    __shared__ int wsum[16];
    int t = threadIdx.x, b = blockIdx.x;
    int e0 = bucketstart[b], e1 = bucketstart[b + 1];
    #pragma unroll
    for (int j = 0; j < KEYS / 1024; ++j) cnt[t + j * 1024] = 0;
    __syncthreads();
    for (int i = e0 + t; i < e1; i += 1024)
        atomicAdd(&cnt[ebuf[i] >> 17], 1u);    // key = dl*32 + et
    __syncthreads();
    int kbase = t * (KEYS / 1024);
    int s = 0;
    #pragma unroll
    for (int j = 0; j < KEYS / 1024; ++j) s += (int)cnt[kbase + j];
    // block-wide exclusive scan of s: wave shuffle scan + 16-wave combine
    int lane = t & 63, wv = t >> 6;
    int sc = s;
    #pragma unroll
    for (int off = 1; off < 64; off <<= 1) {
        int v = __shfl_up(sc, off, 64);
        if (lane >= off) sc += v;
    }
    if (lane == 63) wsum[wv] = sc;
    __syncthreads();
    if (t < 16) {
        int v = wsum[t];
        int sc2 = v;
        #pragma unroll
        for (int off = 1; off < 16; off <<= 1) {
            int u = __shfl_up(sc2, off, 16);
            if (t >= off) sc2 += u;
        }
        wsum[t] = sc2 - v;   // exclusive
    }
    __syncthreads();
    int run = wsum[wv] + sc - s;
    #pragma unroll
    for (int j = 0; j < KEYS / 1024; ++j) {
        unsigned v = cnt[kbase + j];
        unsigned lc = v > 1023u ? 1023u : v;
        cnt[kbase + j] = (unsigned)run | (lc << 20);
        run += (int)v;
    }
    __syncthreads();
    if (t < 256) {
        int d = b * 256 + t;
        if (d < N_NODES) rowstart[d] = e0 + (int)(cnt[t * 32] & 0xFFFFFu);
    }
    __syncthreads();
    for (int i = e0 + t; i < e1; i += 1024) {
        unsigned pk = ebuf[i];
        int key = pk >> 17;
        unsigned vv = atomicAdd(&cnt[key], 1u);
        int pos = (int)(vv & 0xFFFFFu);
        unsigned len = (vv >> 20) & 1023u;
        elist[e0 + pos] = (pk & 0x3FFFFFu) | (len << 22);
    }
}

// ---------------- emb f32 -> bf16, rows padded to M_PAD with zeros ----------------
__global__ __launch_bounds__(256) void k_cvt(const float* __restrict__ emb,
                                             unsigned short* __restrict__ out) {
    int g = blockIdx.x * 256 + threadIdx.x;       // unit of 4 elems
    size_t base = (size_t)g * 4;
    if (base >= (size_t)M_PAD * F_IN) return;
    int row = (int)(base >> 7);
    ushort4 o;
    if (row < N_NODES) {
        float4 a = *(const float4*)(emb + base);
        o.x = f2bf(a.x); o.y = f2bf(a.y); o.z = f2bf(a.z); o.w = f2bf(a.w);
    } else {
        o.x = o.y = o.z = o.w = 0;
    }
    *(ushort4*)(out + base) = o;
}

// ---------------- repack W1 [R,128,16] -> BmT bf16 [512][128] ----------------
__global__ __launch_bounds__(256) void k_prep_w(const float* __restrict__ W1,
                                                unsigned short* __restrict__ BmT) {
    int i = blockIdx.x * 256 + threadIdx.x;   // i = n*128 + f
    if (i >= NOUT * F_IN) return;
    int n = i >> 7;
    int f = i & 127;
    int r = n >> 4;
    int o = n & 15;
    BmT[i] = f2bf(W1[r * (F_IN * HDIM) + f * HDIM + o]);
}

// ---------------- GEMM: xw1[M_PAD,512](bf16) = Abf @ BmT^T, 64x128 tile ----------------
__global__ __launch_bounds__(256) void k_gemm(const unsigned short* __restrict__ Abf,
                                              const unsigned short* __restrict__ BmT,
                                              unsigned short* __restrict__ C) {
    __shared__ unsigned short As[64 * 136];    // 17.4 KB
    __shared__ unsigned short Bs[128 * 136];   // 34.8 KB
    int t = threadIdx.x;
    int row0 = blockIdx.x * 64;
    int col0 = blockIdx.y * 128;

    #pragma unroll
    for (int j = 0; j < 4; ++j) {
        int idx = t + j * 256;            // 0..1023 8-elem units
        int r = idx >> 4;
        int u = idx & 15;
        float4 v = *(const float4*)(Abf + (size_t)(row0 + r) * F_IN + u * 8);
        *(float4*)(&As[r * 136 + u * 8]) = v;
    }
    #pragma unroll
    for (int j = 0; j < 8; ++j) {
        int idx = t + j * 256;            // 0..2047
        int r = idx >> 4;                 // 0..127
        int u = idx & 15;
        float4 v = *(const float4*)(BmT + (size_t)(col0 + r) * F_IN + u * 8);
        *(float4*)(&Bs[r * 136 + u * 8]) = v;
    }
    __syncthreads();

    int w = t >> 6;
    int lane = t & 63;
    int q = lane >> 4;
    int mr = lane & 15;

    f32x4 acc[8] = {};
    const unsigned short* ap = &As[(w * 16 + mr) * 136 + q * 8];
    #pragma unroll
    for (int kk = 0; kk < 4; ++kk) {
        bf16x8 af = *(const bf16x8*)(ap + kk * 32);
        #pragma unroll
        for (int tt = 0; tt < 8; ++tt) {
            bf16x8 bf = *(const bf16x8*)(&Bs[(tt * 16 + mr) * 136 + q * 8 + kk * 32]);
            acc[tt] = __builtin_amdgcn_mfma_f32_16x16x32_bf16(af, bf, acc[tt], 0, 0, 0);
        }
    }
    #pragma unroll
    for (int tt = 0; tt < 8; ++tt) {
        #pragma unroll
        for (int j = 0; j < 4; ++j) {
            int row = row0 + w * 16 + q * 4 + j;
            C[(size_t)row * NOUT + col0 + tt * 16 + mr] = f2bf(acc[tt][j]);
        }
    }
}

// ---------------- layer-1 gather: 8 lanes/node, 2-edge unroll, h f16 out ----------------
__global__ __launch_bounds__(256) void k_gather1(const int* __restrict__ rowstart,
                                                 const unsigned int* __restrict__ elist,
                                                 const unsigned short* __restrict__ xw1,
                                                 _Float16* __restrict__ h) {
    __shared__ float nlut[1024];
    int t = threadIdx.x;
    for (int j = t; j < 1024; j += 256) nlut[j] = 1.0f / (float)(j ? j : 1);
    __syncthreads();
    int g = t >> 3;
    int c = t & 7;
    int d = blockIdx.x * 32 + g;
    if (d >= N_NODES) return;
    int i = rowstart[d], end = rowstart[d + 1];
    float a0 = 0.f, a1 = 0.f, b0 = 0.f, b1 = 0.f;
    for (; i + 1 < end; i += 2) {
        unsigned pk0 = elist[i];
        unsigned pk1 = elist[i + 1];
        int s0 = pk0 & 0x1FFFF, s1 = pk1 & 0x1FFFF;
        int r0 = (pk0 >> 17) & 31, r1 = (pk1 >> 17) & 31;
        float nm0 = nlut[pk0 >> 22], nm1 = nlut[pk1 >> 22];
        unsigned x0 = *(const unsigned*)(xw1 + (size_t)s0 * NOUT + r0 * HDIM + c * 2);
        unsigned x1 = *(const unsigned*)(xw1 + (size_t)s1 * NOUT + r1 * HDIM + c * 2);
        a0 += __uint_as_float(x0 << 16) * nm0;
        a1 += __uint_as_float(x0 & 0xFFFF0000u) * nm0;
        b0 += __uint_as_float(x1 << 16) * nm1;
        b1 += __uint_as_float(x1 & 0xFFFF0000u) * nm1;
    }
    if (i < end) {
        unsigned pk = elist[i];
        int s = pk & 0x1FFFF;
        int r = (pk >> 17) & 31;
        float nm = nlut[pk >> 22];
        unsigned x = *(const unsigned*)(xw1 + (size_t)s * NOUT + r * HDIM + c * 2);
        a0 += __uint_as_float(x << 16) * nm;
        a1 += __uint_as_float(x & 0xFFFF0000u) * nm;
    }
    f16x2 o;
    o.x = (_Float16)fmaxf(a0 + b0, 0.f);
    o.y = (_Float16)fmaxf(a1 + b1, 0.f);
    *(f16x2*)(h + (size_t)d * HDIM + c * 2) = o;
}

// ---------------- layer-2 gather + fused log_softmax: 8 lanes/node, dot2 f16 ----------------
#define W2P 260   // per-class stride in f16x2 units
__global__ __launch_bounds__(256) void k_gather2(const int* __restrict__ rowstart,
                                                 const unsigned int* __restrict__ elist,
                                                 const _Float16* __restrict__ h,
                                                 const float* __restrict__ W2,
                                                 float* __restrict__ out) {
    __shared__ f16x2 sW2h[CDIM * W2P];   // [c][r*8+j], ~8.3 KB
    __shared__ float nlut[1024];
    int t = threadIdx.x;
    for (int j = t; j < 1024; j += 256) nlut[j] = 1.0f / (float)(j ? j : 1);
    #pragma unroll
    for (int j = 0; j < 8; ++j) {
        int idx = t + j * 256;           // 0..2047
        int c = idx >> 8;
        int rem = idx & 255;             // r*8 + jj
        int r = rem >> 3;
        int jj = rem & 7;
        f16x2 p;
        p.x = (_Float16)W2[r * (HDIM * CDIM) + (2 * jj) * CDIM + c];
        p.y = (_Float16)W2[r * (HDIM * CDIM) + (2 * jj + 1) * CDIM + c];
        sW2h[c * W2P + rem] = p;
    }
    __syncthreads();

    int g = t >> 3;
    int c = t & 7;
    int d = blockIdx.x * 32 + g;
    if (d >= N_NODES) return;
    const f16x2* wc = &sW2h[c * W2P];
    int i = rowstart[d], end = rowstart[d + 1];
    float acc0 = 0.f, acc1 = 0.f;
    for (; i + 1 < end; i += 2) {
        unsigned pk0 = elist[i];
        unsigned pk1 = elist[i + 1];
        int s0 = pk0 & 0x1FFFF, s1 = pk1 & 0x1FFFF;
        int r0 = (pk0 >> 17) & 31, r1 = (pk1 >> 17) & 31;
        float nm0 = nlut[pk0 >> 22], nm1 = nlut[pk1 >> 22];
        const float4* hp0 = (const float4*)(h + (size_t)s0 * HDIM);
        const float4* hp1 = (const float4*)(h + (size_t)s1 * HDIM);
        float4 u0 = hp0[0], u1 = hp0[1];
        float4 v0 = hp1[0], v1 = hp1[1];
        const f16x2* wp0 = wc + r0 * 8;
        const f16x2* wp1 = wc + r1 * 8;
        float sd0 = 0.f, sd1 = 0.f;
        sd0 = FDOT2(asf16x2(u0.x), wp0[0], sd0);
        sd0 = FDOT2(asf16x2(u0.y), wp0[1], sd0);
        sd0 = FDOT2(asf16x2(u0.z), wp0[2], sd0);
        sd0 = FDOT2(asf16x2(u0.w), wp0[3], sd0);
        sd0 = FDOT2(asf16x2(u1.x), wp0[4], sd0);
        sd0 = FDOT2(asf16x2(u1.y), wp0[5], sd0);
        sd0 = FDOT2(asf16x2(u1.z), wp0[6], sd0);
        sd0 = FDOT2(asf16x2(u1.w), wp0[7], sd0);
        sd1 = FDOT2(asf16x2(v0.x), wp1[0], sd1);
        sd1 = FDOT2(asf16x2(v0.y), wp1[1], sd1);
        sd1 = FDOT2(asf16x2(v0.z), wp1[2], sd1);
        sd1 = FDOT2(asf16x2(v0.w), wp1[3], sd1);
        sd1 = FDOT2(asf16x2(v1.x), wp1[4], sd1);
        sd1 = FDOT2(asf16x2(v1.y), wp1[5], sd1);
        sd1 = FDOT2(asf16x2(v1.z), wp1[6], sd1);
        sd1 = FDOT2(asf16x2(v1.w), wp1[7], sd1);
        acc0 += nm0 * sd0;
        acc1 += nm1 * sd1;
    }
    if (i < end) {
        unsigned pk = elist[i];
        int s = pk & 0x1FFFF;
        int r = (pk >> 17) & 31;
        float nm = nlut[pk >> 22];
        const float4* hp = (const float4*)(h + (size_t)s * HDIM);
        float4 u0 = hp[0], u1 = hp[1];
        const f16x2* wp = wc + r * 8;
        float sd = 0.f;
        sd = FDOT2(asf16x2(u0.x), wp[0], sd);
        sd = FDOT2(asf16x2(u0.y), wp[1], sd);
        sd = FDOT2(asf16x2(u0.z), wp[2], sd);
        sd = FDOT2(asf16x2(u0.w), wp[3], sd);
        sd = FDOT2(asf16x2(u1.x), wp[4], sd);
        sd = FDOT2(asf16x2(u1.y), wp[5], sd);
        sd = FDOT2(asf16x2(u1.z), wp[6], sd);
        sd = FDOT2(asf16x2(u1.w), wp[7], sd);
        acc0 += nm * sd;
    }
    float acc = acc0 + acc1;
    float m = acc;
    #pragma unroll
    for (int mask = 1; mask < 8; mask <<= 1)
        m = fmaxf(m, __shfl_xor(m, mask, 8));
    float ex = expf(acc - m);
    float ssumv = ex;
    #pragma unroll
    for (int mask = 1; mask < 8; mask <<= 1)
        ssumv += __shfl_xor(ssumv, mask, 8);
    out[(size_t)d * CDIM + c] = acc - m - logf(ssumv);
}

extern "C" void kernel_launch(void* const* d_in, const int* in_sizes, int n_in,
                              void* d_out, int out_size, void* d_ws, size_t ws_size,
                              hipStream_t stream) {
    const float* emb = (const float*)d_in[0];
    const float* W1  = (const float*)d_in[1];
    const float* W2  = (const float*)d_in[2];
    const int* ei    = (const int*)d_in[3];
    const int* et    = (const int*)d_in[4];
    const int* srcp  = ei;
    const int* dstp  = ei + E_EDGES;

    char* ws = (char*)d_ws;
    size_t off = 0;
    #define ALIGN256(x) (((x) + 255) & ~(size_t)255)
    int* bucketcount = (int*)(ws + off); off = ALIGN256(off + 512 * 4);
    int* bucketstart = (int*)(ws + off); off = ALIGN256(off + 512 * 4);
    int* gcursor     = (int*)(ws + off); off = ALIGN256(off + 512 * 4);
    int* rowstart    = (int*)(ws + off); off = ALIGN256(off + ((size_t)N_NODES + 8) * 4);
    unsigned int* ebuf  = (unsigned int*)(ws + off); off = ALIGN256(off + (size_t)E_EDGES * 4);
    unsigned int* elist = (unsigned int*)(ws + off); off = ALIGN256(off + (size_t)E_EDGES * 4);
    unsigned short* BmT  = (unsigned short*)(ws + off); off = ALIGN256(off + (size_t)NOUT * F_IN * 2);
    unsigned short* ebf  = (unsigned short*)(ws + off); off = ALIGN256(off + (size_t)M_PAD * F_IN * 2);
    unsigned short* xw1  = (unsigned short*)(ws + off); off = ALIGN256(off + (size_t)M_PAD * NOUT * 2);
    _Float16* h          = (_Float16*)(ws + off);       off = ALIGN256(off + (size_t)N_NODES * HDIM * 2);
    float* out = (float*)d_out;

    hipMemsetAsync(bucketcount, 0, NBUCK * 4, stream);

    k_hist<<<P1GRID, 512, 0, stream>>>(dstp, bucketcount);
    k_scanb<<<1, 512, 0, stream>>>(bucketcount, bucketstart, gcursor, rowstart);
    k_bucket<<<P1GRID, 512, 0, stream>>>(srcp, dstp, et, gcursor, ebuf);
    k_sortb<<<NBUCK, 1024, 0, stream>>>(ebuf, bucketstart, rowstart, elist);

    k_cvt<<<((M_PAD * F_IN / 4) + 255) / 256, 256, 0, stream>>>(emb, ebf);
    k_prep_w<<<(NOUT * F_IN) / 256, 256, 0, stream>>>(W1, BmT);
    dim3 g_gemm(M_PAD / 64, NOUT / 128);
    k_gemm<<<g_gemm, 256, 0, stream>>>(ebf, BmT, xw1);

    k_gather1<<<(N_NODES + 31) / 32, 256, 0, stream>>>(rowstart, elist, xw1, h);
    k_gather2<<<(N_NODES + 31) / 32, 256, 0, stream>>>(rowstart, elist, h, W2, out);
}

// Round 6
// 332.624 us; speedup vs baseline: 2.5104x; 1.0444x over previous
//
#include <hip/hip_runtime.h>
#include <hip/hip_bf16.h>
#include <math.h>

#define N_NODES 100000
#define R 32
#define E_EDGES 3200000
#define F_IN 128
#define HDIM 16
#define CDIM 8
#define NOUT 512               // R * HDIM
#define M_PAD 100032           // 1563 * 64
#define NBUCK 391              // ceil(N_NODES / 256)
#define CAP 9216               // bucket capacity: mean 8184, +11.4 sigma
#define KEYS 8192              // 256 nodes * 32 rels per bucket
#define P1CHUNK 8192
#define CVT_BLKS 6252          // M_PAD*F_IN/4 / 512
#define PREP_BLKS 128          // NOUT*F_IN / 512
#define FRONT_GRID (NBUCK + CVT_BLKS + PREP_BLKS)
#define GEMM_BLKS 6252         // (M_PAD/64) * (NOUT/128)
#define MID_GRID (NBUCK + GEMM_BLKS)

typedef __attribute__((ext_vector_type(8))) short bf16x8;
typedef __attribute__((ext_vector_type(4))) float f32x4;
typedef __attribute__((ext_vector_type(2))) _Float16 f16x2;
typedef __attribute__((ext_vector_type(4))) _Float16 f16x4;

static __device__ __forceinline__ unsigned short f2bf(float f) {
    unsigned int u = __float_as_uint(f);
    unsigned int r = (u + 0x7FFFu + ((u >> 16) & 1u)) >> 16;
    return (unsigned short)r;
}
static __device__ __forceinline__ float bfl(unsigned x) {
    return __uint_as_float(x << 16);
}
static __device__ __forceinline__ float bfh(unsigned x) {
    return __uint_as_float(x & 0xFFFF0000u);
}
static __device__ __forceinline__ f16x2 asf16x2(float f) {
    union { float f; f16x2 h; } u; u.f = f; return u.h;
}

#if __has_builtin(__builtin_amdgcn_fdot2)
static __device__ __forceinline__ float FDOT2(f16x2 a, f16x2 b, float c) {
    return __builtin_amdgcn_fdot2(a, b, c, false);
}
#else
static __device__ __forceinline__ float FDOT2(f16x2 a, f16x2 b, float c) {
    return c + (float)a.x * (float)b.x + (float)a.y * (float)b.y;
}
#endif

// ============ k_front: bucket-scatter ∥ emb->bf16 cvt ∥ W1 repack ============
// packed ebuf entry: dl(8b)<<22 | et(5b)<<17 | src(17b)
__global__ __launch_bounds__(512) void k_front(const int* __restrict__ src,
                                               const int* __restrict__ dst,
                                               const int* __restrict__ et,
                                               const float* __restrict__ emb,
                                               const float* __restrict__ W1,
                                               int* __restrict__ gcursor,
                                               unsigned int* __restrict__ ebuf,
                                               unsigned short* __restrict__ ebf,
                                               unsigned short* __restrict__ BmT) {
    __shared__ int sh[3 * NBUCK];
    int b = blockIdx.x, t = threadIdx.x;
    if (b < NBUCK) {
        int* hist = sh;
        int* rank = sh + NBUCK;
        int* base = sh + 2 * NBUCK;
        for (int j = t; j < NBUCK; j += 512) { hist[j] = 0; rank[j] = 0; }
        __syncthreads();
        int e0 = b * P1CHUNK;
        int e1 = e0 + P1CHUNK; if (e1 > E_EDGES) e1 = E_EDGES;
        int n4 = (e1 - e0) >> 2;
        const int4* d4 = (const int4*)(dst + e0);
        const int4* s4 = (const int4*)(src + e0);
        const int4* t4 = (const int4*)(et + e0);
        for (int i = t; i < n4; i += 512) {
            int4 v = d4[i];
            atomicAdd(&hist[v.x >> 8], 1);
            atomicAdd(&hist[v.y >> 8], 1);
            atomicAdd(&hist[v.z >> 8], 1);
            atomicAdd(&hist[v.w >> 8], 1);
        }
        __syncthreads();
        for (int j = t; j < NBUCK; j += 512)
            base[j] = hist[j] ? atomicAdd(&gcursor[j], hist[j]) : 0;
        __syncthreads();
        for (int i = t; i < n4; i += 512) {
            int4 dv = d4[i];
            int4 sv = s4[i];
            int4 tv = t4[i];
            int ds[4] = {dv.x, dv.y, dv.z, dv.w};
            int ss[4] = {sv.x, sv.y, sv.z, sv.w};
            int ts[4] = {tv.x, tv.y, tv.z, tv.w};
            #pragma unroll
            for (int u = 0; u < 4; ++u) {
                int d = ds[u];
                int bk = d >> 8;
                unsigned pk = ((unsigned)(d & 255) << 22) | ((unsigned)ts[u] << 17)
                            | (unsigned)ss[u];
                int lr = atomicAdd(&rank[bk], 1);
                ebuf[(size_t)bk * CAP + base[bk] + lr] = pk;
            }
        }
    } else if (b < NBUCK + CVT_BLKS) {
        // emb f32 -> bf16, rows padded to M_PAD with zeros; 1 float4-unit/thread
        size_t base = ((size_t)(b - NBUCK) * 512 + t) * 4;
        int row = (int)(base >> 7);
        ushort4 o;
        if (row < N_NODES) {
            float4 a = *(const float4*)(emb + base);
            o.x = f2bf(a.x); o.y = f2bf(a.y); o.z = f2bf(a.z); o.w = f2bf(a.w);
        } else {
            o.x = o.y = o.z = o.w = 0;
        }
        *(ushort4*)(ebf + base) = o;
    } else {
        // W1 [R,128,16] -> BmT bf16 [512][128] (n=r*16+o, k=f)
        int i = (b - NBUCK - CVT_BLKS) * 512 + t;
        int n = i >> 7;
        int f = i & 127;
        int r = n >> 4;
        int o = n & 15;
        BmT[i] = f2bf(W1[r * (F_IN * HDIM) + f * HDIM + o]);
    }
}

// ============ k_scanb: exclusive scan of bucket counts ============
__global__ __launch_bounds__(512) void k_scanb(const int* __restrict__ gcursor,
                                               int* __restrict__ bucketstart,
                                               int* __restrict__ rowstart) {
    __shared__ int sb[NBUCK + 1];
    int t = threadIdx.x;
    if (t == 0) {
        int acc = 0;
        for (int b = 0; b < NBUCK; ++b) { int v = gcursor[b]; sb[b] = acc; acc += v; }
        sb[NBUCK] = acc;
        rowstart[N_NODES] = acc;   // == E_EDGES
    }
    __syncthreads();
    for (int j = t; j <= NBUCK; j += 512) bucketstart[j] = sb[j];
}

// ============ k_mid: per-bucket counting sort ∥ MFMA GEMM ============
// final elist entry: len(10b)<<22 | et(5b)<<17 | src(17b)
__global__ __launch_bounds__(256) void k_mid(const unsigned int* __restrict__ ebuf,
                                             const int* __restrict__ gcursor,
                                             const int* __restrict__ bucketstart,
                                             int* __restrict__ rowstart,
                                             unsigned int* __restrict__ elist,
                                             const unsigned short* __restrict__ Abf,
                                             const unsigned short* __restrict__ BmT,
                                             unsigned short* __restrict__ C) {
    __shared__ __align__(16) char smem[52224 + 64];
    int b = blockIdx.x, t = threadIdx.x;
    if (b < NBUCK) {
        // ---- counting sort, 256 threads ----
        unsigned int* cnt = (unsigned int*)smem;       // 8192 * 4 = 32 KB
        int* wsum = (int*)(smem + 32768);              // 4 ints
        int cntE = gcursor[b];
        size_t esrc = (size_t)b * CAP;
        int e0 = bucketstart[b];
        #pragma unroll
        for (int j = 0; j < KEYS / 256; ++j) cnt[t + j * 256] = 0;
        __syncthreads();
        for (int i = t; i < cntE; i += 256)
            atomicAdd(&cnt[ebuf[esrc + i] >> 17], 1u);  // key = dl*32 + et
        __syncthreads();
        int kbase = t * (KEYS / 256);
        int s = 0;
        #pragma unroll
        for (int j = 0; j < KEYS / 256; ++j) s += (int)cnt[kbase + j];
        int lane = t & 63, wv = t >> 6;
        int sc = s;
        #pragma unroll
        for (int off = 1; off < 64; off <<= 1) {
            int v = __shfl_up(sc, off, 64);
            if (lane >= off) sc += v;
        }
        if (lane == 63) wsum[wv] = sc;
        __syncthreads();
        if (t == 0) {
            int a = 0;
            #pragma unroll
            for (int w = 0; w < 4; ++w) { int v = wsum[w]; wsum[w] = a; a += v; }
        }
        __syncthreads();
        int run = wsum[wv] + sc - s;
        #pragma unroll
        for (int j = 0; j < KEYS / 256; ++j) {
            unsigned v = cnt[kbase + j];
            unsigned lc = v > 1023u ? 1023u : v;
            cnt[kbase + j] = (unsigned)run | (lc << 20);
            run += (int)v;
        }
        __syncthreads();
        {
            int d = b * 256 + t;
            if (d < N_NODES) rowstart[d] = e0 + (int)(cnt[t * 32] & 0xFFFFFu);
        }
        __syncthreads();
        for (int i = t; i < cntE; i += 256) {
            unsigned pk = ebuf[esrc + i];
            int key = pk >> 17;
            unsigned vv = atomicAdd(&cnt[key], 1u);
            int pos = (int)(vv & 0xFFFFFu);
            unsigned len = (vv >> 20) & 1023u;
            elist[e0 + pos] = (pk & 0x3FFFFFu) | (len << 22);
        }
    } else {
        // ---- GEMM 64x128 tile: xw1 = Abf @ BmT^T ----
        unsigned short* As = (unsigned short*)smem;            // 64*136*2  = 17408
        unsigned short* Bs = (unsigned short*)(smem + 17408);  // 128*136*2 = 34816
        int bb = b - NBUCK;
        int row0 = (bb >> 2) * 64;
        int col0 = (bb & 3) * 128;
        #pragma unroll
        for (int j = 0; j < 4; ++j) {
            int idx = t + j * 256;            // 0..1023 8-elem units
            int r = idx >> 4;
            int u = idx & 15;
            float4 v = *(const float4*)(Abf + (size_t)(row0 + r) * F_IN + u * 8);
            *(float4*)(&As[r * 136 + u * 8]) = v;
        }
        #pragma unroll
        for (int j = 0; j < 8; ++j) {
            int idx = t + j * 256;            // 0..2047
            int r = idx >> 4;                 // 0..127
            int u = idx & 15;
            float4 v = *(const float4*)(BmT + (size_t)(col0 + r) * F_IN + u * 8);
            *(float4*)(&Bs[r * 136 + u * 8]) = v;
        }
        __syncthreads();
        int w = t >> 6;
        int lane = t & 63;
        int q = lane >> 4;
        int mr = lane & 15;
        f32x4 acc[8] = {};
        const unsigned short* ap = &As[(w * 16 + mr) * 136 + q * 8];
        #pragma unroll
        for (int kk = 0; kk < 4; ++kk) {
            bf16x8 af = *(const bf16x8*)(ap + kk * 32);
            #pragma unroll
            for (int tt = 0; tt < 8; ++tt) {
                bf16x8 bf = *(const bf16x8*)(&Bs[(tt * 16 + mr) * 136 + q * 8 + kk * 32]);
                acc[tt] = __builtin_amdgcn_mfma_f32_16x16x32_bf16(af, bf, acc[tt], 0, 0, 0);
            }
        }
        #pragma unroll
        for (int tt = 0; tt < 8; ++tt) {
            #pragma unroll
            for (int j = 0; j < 4; ++j) {
                int row = row0 + w * 16 + q * 4 + j;
                C[(size_t)row * NOUT + col0 + tt * 16 + mr] = f2bf(acc[tt][j]);
            }
        }
    }
}

// ============ gather1: 4 lanes/node, 8 B loads, 4-edge unroll, h f16 ============
__global__ __launch_bounds__(256) void k_gather1(const int* __restrict__ rowstart,
                                                 const unsigned int* __restrict__ elist,
                                                 const unsigned short* __restrict__ xw1,
                                                 _Float16* __restrict__ h) {
    __shared__ float nlut[1024];
    int t = threadIdx.x;
    for (int j = t; j < 1024; j += 256) nlut[j] = 1.0f / (float)(j ? j : 1);
    __syncthreads();
    int g = t >> 2;            // node in block, 0..63
    int c = t & 3;             // channel group: elems c*4 .. c*4+3
    int d = blockIdx.x * 64 + g;
    if (d >= N_NODES) return;
    int i = rowstart[d], end = rowstart[d + 1];
    float a0 = 0.f, a1 = 0.f, a2 = 0.f, a3 = 0.f;
    for (; i + 3 < end; i += 4) {
        unsigned pk0 = elist[i];
        unsigned pk1 = elist[i + 1];
        unsigned pk2 = elist[i + 2];
        unsigned pk3 = elist[i + 3];
        uint2 x0 = *(const uint2*)(xw1 + (size_t)(pk0 & 0x1FFFF) * NOUT + ((pk0 >> 17) & 31) * HDIM + c * 4);
        uint2 x1 = *(const uint2*)(xw1 + (size_t)(pk1 & 0x1FFFF) * NOUT + ((pk1 >> 17) & 31) * HDIM + c * 4);
        uint2 x2 = *(const uint2*)(xw1 + (size_t)(pk2 & 0x1FFFF) * NOUT + ((pk2 >> 17) & 31) * HDIM + c * 4);
        uint2 x3 = *(const uint2*)(xw1 + (size_t)(pk3 & 0x1FFFF) * NOUT + ((pk3 >> 17) & 31) * HDIM + c * 4);
        float n0 = nlut[pk0 >> 22], n1 = nlut[pk1 >> 22];
        float n2 = nlut[pk2 >> 22], n3 = nlut[pk3 >> 22];
        a0 += bfl(x0.x) * n0; a1 += bfh(x0.x) * n0; a2 += bfl(x0.y) * n0; a3 += bfh(x0.y) * n0;
        a0 += bfl(x1.x) * n1; a1 += bfh(x1.x) * n1; a2 += bfl(x1.y) * n1; a3 += bfh(x1.y) * n1;
        a0 += bfl(x2.x) * n2; a1 += bfh(x2.x) * n2; a2 += bfl(x2.y) * n2; a3 += bfh(x2.y) * n2;
        a0 += bfl(x3.x) * n3; a1 += bfh(x3.x) * n3; a2 += bfl(x3.y) * n3; a3 += bfh(x3.y) * n3;
    }
    for (; i < end; ++i) {
        unsigned pk = elist[i];
        uint2 x = *(const uint2*)(xw1 + (size_t)(pk & 0x1FFFF) * NOUT + ((pk >> 17) & 31) * HDIM + c * 4);
        float nm = nlut[pk >> 22];
        a0 += bfl(x.x) * nm; a1 += bfh(x.x) * nm; a2 += bfl(x.y) * nm; a3 += bfh(x.y) * nm;
    }
    f16x4 o;
    o.x = (_Float16)fmaxf(a0, 0.f);
    o.y = (_Float16)fmaxf(a1, 0.f);
    o.z = (_Float16)fmaxf(a2, 0.f);
    o.w = (_Float16)fmaxf(a3, 0.f);
    *(f16x4*)(h + (size_t)d * HDIM + c * 4) = o;
}

// ============ gather2 + fused log_softmax: 8 lanes/node, dot2, 2-edge unroll ============
#define W2P 260   // per-class stride in f16x2 units
__global__ __launch_bounds__(256) void k_gather2(const int* __restrict__ rowstart,
                                                 const unsigned int* __restrict__ elist,
                                                 const _Float16* __restrict__ h,
                                                 const float* __restrict__ W2,
                                                 float* __restrict__ out) {
    __shared__ f16x2 sW2h[CDIM * W2P];
    __shared__ float nlut[1024];
    int t = threadIdx.x;
    for (int j = t; j < 1024; j += 256) nlut[j] = 1.0f / (float)(j ? j : 1);
    #pragma unroll
    for (int j = 0; j < 8; ++j) {
        int idx = t + j * 256;           // 0..2047
        int c = idx >> 8;
        int rem = idx & 255;             // r*8 + jj
        int r = rem >> 3;
        int jj = rem & 7;
        f16x2 p;
        p.x = (_Float16)W2[r * (HDIM * CDIM) + (2 * jj) * CDIM + c];
        p.y = (_Float16)W2[r * (HDIM * CDIM) + (2 * jj + 1) * CDIM + c];
        sW2h[c * W2P + rem] = p;
    }
    __syncthreads();

    int g = t >> 3;
    int c = t & 7;
    int d = blockIdx.x * 32 + g;
    if (d >= N_NODES) return;
    const f16x2* wc = &sW2h[c * W2P];
    int i = rowstart[d], end = rowstart[d + 1];
    float acc0 = 0.f, acc1 = 0.f;
    for (; i + 1 < end; i += 2) {
        unsigned pk0 = elist[i];
        unsigned pk1 = elist[i + 1];
        const float4* hp0 = (const float4*)(h + (size_t)(pk0 & 0x1FFFF) * HDIM);
        const float4* hp1 = (const float4*)(h + (size_t)(pk1 & 0x1FFFF) * HDIM);
        float4 u0 = hp0[0], u1 = hp0[1];
        float4 v0 = hp1[0], v1 = hp1[1];
        float nm0 = nlut[pk0 >> 22], nm1 = nlut[pk1 >> 22];
        const f16x2* wp0 = wc + ((pk0 >> 17) & 31) * 8;
        const f16x2* wp1 = wc + ((pk1 >> 17) & 31) * 8;
        float sd0 = 0.f, sd1 = 0.f;
        sd0 = FDOT2(asf16x2(u0.x), wp0[0], sd0);
        sd0 = FDOT2(asf16x2(u0.y), wp0[1], sd0);
        sd0 = FDOT2(asf16x2(u0.z), wp0[2], sd0);
        sd0 = FDOT2(asf16x2(u0.w), wp0[3], sd0);
        sd0 = FDOT2(asf16x2(u1.x), wp0[4], sd0);
        sd0 = FDOT2(asf16x2(u1.y), wp0[5], sd0);
        sd0 = FDOT2(asf16x2(u1.z), wp0[6], sd0);
        sd0 = FDOT2(asf16x2(u1.w), wp0[7], sd0);
        sd1 = FDOT2(asf16x2(v0.x), wp1[0], sd1);
        sd1 = FDOT2(asf16x2(v0.y), wp1[1], sd1);
        sd1 = FDOT2(asf16x2(v0.z), wp1[2], sd1);
        sd1 = FDOT2(asf16x2(v0.w), wp1[3], sd1);
        sd1 = FDOT2(asf16x2(v1.x), wp1[4], sd1);
        sd1 = FDOT2(asf16x2(v1.y), wp1[5], sd1);
        sd1 = FDOT2(asf16x2(v1.z), wp1[6], sd1);
        sd1 = FDOT2(asf16x2(v1.w), wp1[7], sd1);
        acc0 += nm0 * sd0;
        acc1 += nm1 * sd1;
    }
    if (i < end) {
        unsigned pk = elist[i];
        const float4* hp = (const float4*)(h + (size_t)(pk & 0x1FFFF) * HDIM);
        float4 u0 = hp[0], u1 = hp[1];
        float nm = nlut[pk >> 22];
        const f16x2* wp = wc + ((pk >> 17) & 31) * 8;
        float sd = 0.f;
        sd = FDOT2(asf16x2(u0.x), wp[0], sd);
        sd = FDOT2(asf16x2(u0.y), wp[1], sd);
        sd = FDOT2(asf16x2(u0.z), wp[2], sd);
        sd = FDOT2(asf16x2(u0.w), wp[3], sd);
        sd = FDOT2(asf16x2(u1.x), wp[4], sd);
        sd = FDOT2(asf16x2(u1.y), wp[5], sd);
        sd = FDOT2(asf16x2(u1.z), wp[6], sd);
        sd = FDOT2(asf16x2(u1.w), wp[7], sd);
        acc0 += nm * sd;
    }
    float acc = acc0 + acc1;
    float m = acc;
    #pragma unroll
    for (int mask = 1; mask < 8; mask <<= 1)
        m = fmaxf(m, __shfl_xor(m, mask, 8));
    float ex = expf(acc - m);
    float ssumv = ex;
    #pragma unroll
    for (int mask = 1; mask < 8; mask <<= 1)
        ssumv += __shfl_xor(ssumv, mask, 8);
    out[(size_t)d * CDIM + c] = acc - m - logf(ssumv);
}

extern "C" void kernel_launch(void* const* d_in, const int* in_sizes, int n_in,
                              void* d_out, int out_size, void* d_ws, size_t ws_size,
                              hipStream_t stream) {
    const float* emb = (const float*)d_in[0];
    const float* W1  = (const float*)d_in[1];
    const float* W2  = (const float*)d_in[2];
    const int* ei    = (const int*)d_in[3];
    const int* et    = (const int*)d_in[4];
    const int* srcp  = ei;
    const int* dstp  = ei + E_EDGES;

    char* ws = (char*)d_ws;
    size_t off = 0;
    #define ALIGN256(x) (((x) + 255) & ~(size_t)255)
    int* gcursor     = (int*)(ws + off); off = ALIGN256(off + 512 * 4);
    int* bucketstart = (int*)(ws + off); off = ALIGN256(off + 512 * 4);
    int* rowstart    = (int*)(ws + off); off = ALIGN256(off + ((size_t)N_NODES + 8) * 4);
    unsigned int* ebuf  = (unsigned int*)(ws + off); off = ALIGN256(off + (size_t)NBUCK * CAP * 4);
    unsigned int* elist = (unsigned int*)(ws + off); off = ALIGN256(off + (size_t)E_EDGES * 4);
    unsigned short* BmT  = (unsigned short*)(ws + off); off = ALIGN256(off + (size_t)NOUT * F_IN * 2);
    unsigned short* ebf  = (unsigned short*)(ws + off); off = ALIGN256(off + (size_t)M_PAD * F_IN * 2);
    unsigned short* xw1  = (unsigned short*)(ws + off); off = ALIGN256(off + (size_t)M_PAD * NOUT * 2);
    _Float16* h          = (_Float16*)(ws + off);       off = ALIGN256(off + (size_t)N_NODES * HDIM * 2);
    float* out = (float*)d_out;

    hipMemsetAsync(gcursor, 0, 512 * 4, stream);

    k_front<<<FRONT_GRID, 512, 0, stream>>>(srcp, dstp, et, emb, W1, gcursor, ebuf, ebf, BmT);
    k_scanb<<<1, 512, 0, stream>>>(gcursor, bucketstart, rowstart);
    k_mid<<<MID_GRID, 256, 0, stream>>>(ebuf, gcursor, bucketstart, rowstart, elist, ebf, BmT, xw1);
    k_gather1<<<(N_NODES + 63) / 64, 256, 0, stream>>>(rowstart, elist, xw1, h);
    k_gather2<<<(N_NODES + 31) / 32, 256, 0, stream>>>(rowstart, elist, h, W2, out);
}

// Round 7
// 328.303 us; speedup vs baseline: 2.5434x; 1.0132x over previous
//
#include <hip/hip_runtime.h>
#include <hip/hip_bf16.h>
#include <math.h>

#define N_NODES 100000
#define R 32
#define E_EDGES 3200000
#define F_IN 128
#define HDIM 16
#define CDIM 8
#define NOUT 512               // R * HDIM
#define M_PAD 100032           // 1563 * 64
#define NBUCK 391              // ceil(N_NODES / 256)
#define CAP 9216               // bucket capacity: mean 8184, +11.4 sigma
#define KEYS 8192              // 256 nodes * 32 rels per bucket
#define P1CHUNK 8192
#define CVT_BLKS 6252          // M_PAD*F_IN/4 / 512
#define PREP_BLKS 128          // NOUT*F_IN / 512
#define FRONT_GRID (NBUCK + CVT_BLKS + PREP_BLKS)
#define GEMM_BLKS 1563         // M_PAD/64  (A-stationary: col loop inside)
#define MID_GRID (NBUCK + GEMM_BLKS)

typedef __attribute__((ext_vector_type(8))) short bf16x8;
typedef __attribute__((ext_vector_type(4))) float f32x4;
typedef __attribute__((ext_vector_type(2))) _Float16 f16x2;

static __device__ __forceinline__ unsigned short f2bf(float f) {
    unsigned int u = __float_as_uint(f);
    unsigned int r = (u + 0x7FFFu + ((u >> 16) & 1u)) >> 16;
    return (unsigned short)r;
}
static __device__ __forceinline__ float bfl(unsigned x) {
    return __uint_as_float(x << 16);
}
static __device__ __forceinline__ float bfh(unsigned x) {
    return __uint_as_float(x & 0xFFFF0000u);
}
static __device__ __forceinline__ f16x2 asf16x2(float f) {
    union { float f; f16x2 h; } u; u.f = f; return u.h;
}

#if __has_builtin(__builtin_amdgcn_fdot2)
static __device__ __forceinline__ float FDOT2(f16x2 a, f16x2 b, float c) {
    return __builtin_amdgcn_fdot2(a, b, c, false);
}
#else
static __device__ __forceinline__ float FDOT2(f16x2 a, f16x2 b, float c) {
    return c + (float)a.x * (float)b.x + (float)a.y * (float)b.y;
}
#endif

// ============ k_front: bucket-scatter ∥ emb->bf16 cvt ∥ W1 repack ============
// packed ebuf entry: dl(8b)<<22 | et(5b)<<17 | src(17b)
__global__ __launch_bounds__(512) void k_front(const int* __restrict__ src,
                                               const int* __restrict__ dst,
                                               const int* __restrict__ et,
                                               const float* __restrict__ emb,
                                               const float* __restrict__ W1,
                                               int* __restrict__ gcursor,
                                               unsigned int* __restrict__ ebuf,
                                               unsigned short* __restrict__ ebf,
                                               unsigned short* __restrict__ BmT) {
    __shared__ int sh[3 * NBUCK];
    int b = blockIdx.x, t = threadIdx.x;
    if (b < NBUCK) {
        int* hist = sh;
        int* rank = sh + NBUCK;
        int* base = sh + 2 * NBUCK;
        for (int j = t; j < NBUCK; j += 512) { hist[j] = 0; rank[j] = 0; }
        __syncthreads();
        int e0 = b * P1CHUNK;
        int e1 = e0 + P1CHUNK; if (e1 > E_EDGES) e1 = E_EDGES;
        int n4 = (e1 - e0) >> 2;
        const int4* d4 = (const int4*)(dst + e0);
        const int4* s4 = (const int4*)(src + e0);
        const int4* t4 = (const int4*)(et + e0);
        for (int i = t; i < n4; i += 512) {
            int4 v = d4[i];
            atomicAdd(&hist[v.x >> 8], 1);
            atomicAdd(&hist[v.y >> 8], 1);
            atomicAdd(&hist[v.z >> 8], 1);
            atomicAdd(&hist[v.w >> 8], 1);
        }
        __syncthreads();
        for (int j = t; j < NBUCK; j += 512)
            base[j] = hist[j] ? atomicAdd(&gcursor[j], hist[j]) : 0;
        __syncthreads();
        for (int i = t; i < n4; i += 512) {
            int4 dv = d4[i];
            int4 sv = s4[i];
            int4 tv = t4[i];
            int ds[4] = {dv.x, dv.y, dv.z, dv.w};
            int ss[4] = {sv.x, sv.y, sv.z, sv.w};
            int ts[4] = {tv.x, tv.y, tv.z, tv.w};
            #pragma unroll
            for (int u = 0; u < 4; ++u) {
                int d = ds[u];
                int bk = d >> 8;
                unsigned pk = ((unsigned)(d & 255) << 22) | ((unsigned)ts[u] << 17)
                            | (unsigned)ss[u];
                int lr = atomicAdd(&rank[bk], 1);
                ebuf[(size_t)bk * CAP + base[bk] + lr] = pk;
            }
        }
    } else if (b < NBUCK + CVT_BLKS) {
        // emb f32 -> bf16, rows padded to M_PAD with zeros; 1 float4-unit/thread
        size_t base = ((size_t)(b - NBUCK) * 512 + t) * 4;
        int row = (int)(base >> 7);
        ushort4 o;
        if (row < N_NODES) {
            float4 a = *(const float4*)(emb + base);
            o.x = f2bf(a.x); o.y = f2bf(a.y); o.z = f2bf(a.z); o.w = f2bf(a.w);
        } else {
            o.x = o.y = o.z = o.w = 0;
        }
        *(ushort4*)(ebf + base) = o;
    } else {
        // W1 [R,128,16] -> BmT bf16 [512][128] (n=r*16+o, k=f)
        int i = (b - NBUCK - CVT_BLKS) * 512 + t;
        int n = i >> 7;
        int f = i & 127;
        int r = n >> 4;
        int o = n & 15;
        BmT[i] = f2bf(W1[r * (F_IN * HDIM) + f * HDIM + o]);
    }
}

// ============ k_scanb: exclusive scan of bucket counts ============
__global__ __launch_bounds__(512) void k_scanb(const int* __restrict__ gcursor,
                                               int* __restrict__ bucketstart,
                                               int* __restrict__ rowstart) {
    __shared__ int sb[NBUCK + 1];
    int t = threadIdx.x;
    if (t == 0) {
        int acc = 0;
        for (int b = 0; b < NBUCK; ++b) { int v = gcursor[b]; sb[b] = acc; acc += v; }
        sb[NBUCK] = acc;
        rowstart[N_NODES] = acc;   // == E_EDGES
    }
    __syncthreads();
    for (int j = t; j <= NBUCK; j += 512) bucketstart[j] = sb[j];
}

// ============ k_mid: per-bucket counting sort ∥ A-stationary MFMA GEMM ============
// final elist entry: len(10b)<<22 | et(5b)<<17 | src(17b)
__global__ __launch_bounds__(256) void k_mid(const unsigned int* __restrict__ ebuf,
                                             const int* __restrict__ gcursor,
                                             const int* __restrict__ bucketstart,
                                             int* __restrict__ rowstart,
                                             unsigned int* __restrict__ elist,
                                             const unsigned short* __restrict__ Abf,
                                             const unsigned short* __restrict__ BmT,
                                             unsigned short* __restrict__ C) {
    __shared__ __align__(16) char smem[52224 + 64];
    int b = blockIdx.x, t = threadIdx.x;
    if (b < NBUCK) {
        // ---- counting sort, 256 threads ----
        unsigned int* cnt = (unsigned int*)smem;       // 8192 * 4 = 32 KB
        int* wsum = (int*)(smem + 32768);              // 4 ints
        int cntE = gcursor[b];
        size_t esrc = (size_t)b * CAP;
        int e0 = bucketstart[b];
        #pragma unroll
        for (int j = 0; j < KEYS / 256; ++j) cnt[t + j * 256] = 0;
        __syncthreads();
        for (int i = t; i < cntE; i += 256)
            atomicAdd(&cnt[ebuf[esrc + i] >> 17], 1u);  // key = dl*32 + et
        __syncthreads();
        int kbase = t * (KEYS / 256);
        int s = 0;
        #pragma unroll
        for (int j = 0; j < KEYS / 256; ++j) s += (int)cnt[kbase + j];
        int lane = t & 63, wv = t >> 6;
        int sc = s;
        #pragma unroll
        for (int off = 1; off < 64; off <<= 1) {
            int v = __shfl_up(sc, off, 64);
            if (lane >= off) sc += v;
        }
        if (lane == 63) wsum[wv] = sc;
        __syncthreads();
        if (t == 0) {
            int a = 0;
            #pragma unroll
            for (int w = 0; w < 4; ++w) { int v = wsum[w]; wsum[w] = a; a += v; }
        }
        __syncthreads();
        int run = wsum[wv] + sc - s;
        #pragma unroll
        for (int j = 0; j < KEYS / 256; ++j) {
            unsigned v = cnt[kbase + j];
            unsigned lc = v > 1023u ? 1023u : v;
            cnt[kbase + j] = (unsigned)run | (lc << 20);
            run += (int)v;
        }
        __syncthreads();
        {
            int d = b * 256 + t;
            if (d < N_NODES) rowstart[d] = e0 + (int)(cnt[t * 32] & 0xFFFFFu);
        }
        __syncthreads();
        for (int i = t; i < cntE; i += 256) {
            unsigned pk = ebuf[esrc + i];
            int key = pk >> 17;
            unsigned vv = atomicAdd(&cnt[key], 1u);
            int pos = (int)(vv & 0xFFFFFu);
            unsigned len = (vv >> 20) & 1023u;
            elist[e0 + pos] = (pk & 0x3FFFFFu) | (len << 22);
        }
    } else {
        // ---- A-stationary GEMM: stage 64x128 A once, loop 4 col-tiles of B ----
        unsigned short* As = (unsigned short*)smem;            // 64*136*2  = 17408
        unsigned short* Bs = (unsigned short*)(smem + 17408);  // 128*136*2 = 34816
        int row0 = (b - NBUCK) * 64;
        #pragma unroll
        for (int j = 0; j < 4; ++j) {
            int idx = t + j * 256;            // 0..1023 8-elem units
            int r = idx >> 4;
            int u = idx & 15;
            float4 v = *(const float4*)(Abf + (size_t)(row0 + r) * F_IN + u * 8);
            *(float4*)(&As[r * 136 + u * 8]) = v;
        }
        int w = t >> 6;
        int lane = t & 63;
        int q = lane >> 4;
        int mr = lane & 15;
        const unsigned short* ap = &As[(w * 16 + mr) * 136 + q * 8];
        for (int col0 = 0; col0 < NOUT; col0 += 128) {
            __syncthreads();   // Bs free from previous iteration (also covers As stage on first)
            #pragma unroll
            for (int j = 0; j < 8; ++j) {
                int idx = t + j * 256;            // 0..2047
                int r = idx >> 4;                 // 0..127
                int u = idx & 15;
                float4 v = *(const float4*)(BmT + (size_t)(col0 + r) * F_IN + u * 8);
                *(float4*)(&Bs[r * 136 + u * 8]) = v;
            }
            __syncthreads();
            f32x4 acc[8] = {};
            #pragma unroll
            for (int kk = 0; kk < 4; ++kk) {
                bf16x8 af = *(const bf16x8*)(ap + kk * 32);
                #pragma unroll
                for (int tt = 0; tt < 8; ++tt) {
                    bf16x8 bf = *(const bf16x8*)(&Bs[(tt * 16 + mr) * 136 + q * 8 + kk * 32]);
                    acc[tt] = __builtin_amdgcn_mfma_f32_16x16x32_bf16(af, bf, acc[tt], 0, 0, 0);
                }
            }
            #pragma unroll
            for (int tt = 0; tt < 8; ++tt) {
                #pragma unroll
                for (int j = 0; j < 4; ++j) {
                    int row = row0 + w * 16 + q * 4 + j;
                    C[(size_t)row * NOUT + col0 + tt * 16 + mr] = f2bf(acc[tt][j]);
                }
            }
        }
    }
}

// ============ gather1: 8 lanes/node, 4 B loads, 4-edge unroll, h f16 ============
__global__ __launch_bounds__(256) void k_gather1(const int* __restrict__ rowstart,
                                                 const unsigned int* __restrict__ elist,
                                                 const unsigned short* __restrict__ xw1,
                                                 _Float16* __restrict__ h) {
    __shared__ float nlut[1024];
    int t = threadIdx.x;
    for (int j = t; j < 1024; j += 256) nlut[j] = 1.0f / (float)(j ? j : 1);
    __syncthreads();
    int g = t >> 3;            // node in block, 0..31
    int c = t & 7;             // channel pair: elems c*2, c*2+1
    int d = blockIdx.x * 32 + g;
    if (d >= N_NODES) return;
    int i = rowstart[d], end = rowstart[d + 1];
    float a0 = 0.f, a1 = 0.f, b0 = 0.f, b1 = 0.f;
    float c0 = 0.f, c1 = 0.f, e0 = 0.f, e1 = 0.f;
    for (; i + 3 < end; i += 4) {
        unsigned pk0 = elist[i];
        unsigned pk1 = elist[i + 1];
        unsigned pk2 = elist[i + 2];
        unsigned pk3 = elist[i + 3];
        unsigned x0 = *(const unsigned*)(xw1 + (size_t)(pk0 & 0x1FFFF) * NOUT + ((pk0 >> 17) & 31) * HDIM + c * 2);
        unsigned x1 = *(const unsigned*)(xw1 + (size_t)(pk1 & 0x1FFFF) * NOUT + ((pk1 >> 17) & 31) * HDIM + c * 2);
        unsigned x2 = *(const unsigned*)(xw1 + (size_t)(pk2 & 0x1FFFF) * NOUT + ((pk2 >> 17) & 31) * HDIM + c * 2);
        unsigned x3 = *(const unsigned*)(xw1 + (size_t)(pk3 & 0x1FFFF) * NOUT + ((pk3 >> 17) & 31) * HDIM + c * 2);
        float n0 = nlut[pk0 >> 22], n1 = nlut[pk1 >> 22];
        float n2 = nlut[pk2 >> 22], n3 = nlut[pk3 >> 22];
        a0 += bfl(x0) * n0; a1 += bfh(x0) * n0;
        b0 += bfl(x1) * n1; b1 += bfh(x1) * n1;
        c0 += bfl(x2) * n2; c1 += bfh(x2) * n2;
        e0 += bfl(x3) * n3; e1 += bfh(x3) * n3;
    }
    for (; i < end; ++i) {
        unsigned pk = elist[i];
        unsigned x = *(const unsigned*)(xw1 + (size_t)(pk & 0x1FFFF) * NOUT + ((pk >> 17) & 31) * HDIM + c * 2);
        float nm = nlut[pk >> 22];
        a0 += bfl(x) * nm; a1 += bfh(x) * nm;
    }
    f16x2 o;
    o.x = (_Float16)fmaxf(a0 + b0 + c0 + e0, 0.f);
    o.y = (_Float16)fmaxf(a1 + b1 + c1 + e1, 0.f);
    *(f16x2*)(h + (size_t)d * HDIM + c * 2) = o;
}

// ============ gather2 + fused log_softmax: 8 lanes/node, dot2, 4-edge unroll ============
#define W2P 260   // per-class stride in f16x2 units
__global__ __launch_bounds__(256) void k_gather2(const int* __restrict__ rowstart,
                                                 const unsigned int* __restrict__ elist,
                                                 const _Float16* __restrict__ h,
                                                 const float* __restrict__ W2,
                                                 float* __restrict__ out) {
    __shared__ f16x2 sW2h[CDIM * W2P];
    __shared__ float nlut[1024];
    int t = threadIdx.x;
    for (int j = t; j < 1024; j += 256) nlut[j] = 1.0f / (float)(j ? j : 1);
    #pragma unroll
    for (int j = 0; j < 8; ++j) {
        int idx = t + j * 256;           // 0..2047
        int c = idx >> 8;
        int rem = idx & 255;             // r*8 + jj
        int r = rem >> 3;
        int jj = rem & 7;
        f16x2 p;
        p.x = (_Float16)W2[r * (HDIM * CDIM) + (2 * jj) * CDIM + c];
        p.y = (_Float16)W2[r * (HDIM * CDIM) + (2 * jj + 1) * CDIM + c];
        sW2h[c * W2P + rem] = p;
    }
    __syncthreads();

    int g = t >> 3;
    int c = t & 7;
    int d = blockIdx.x * 32 + g;
    if (d >= N_NODES) return;
    const f16x2* wc = &sW2h[c * W2P];
    int i = rowstart[d], end = rowstart[d + 1];
    float acc0 = 0.f, acc1 = 0.f, acc2 = 0.f, acc3 = 0.f;
    for (; i + 3 < end; i += 4) {
        unsigned pk0 = elist[i];
        unsigned pk1 = elist[i + 1];
        unsigned pk2 = elist[i + 2];
        unsigned pk3 = elist[i + 3];
        const float4* hp0 = (const float4*)(h + (size_t)(pk0 & 0x1FFFF) * HDIM);
        const float4* hp1 = (const float4*)(h + (size_t)(pk1 & 0x1FFFF) * HDIM);
        const float4* hp2 = (const float4*)(h + (size_t)(pk2 & 0x1FFFF) * HDIM);
        const float4* hp3 = (const float4*)(h + (size_t)(pk3 & 0x1FFFF) * HDIM);
        float4 u0 = hp0[0], u1 = hp0[1];
        float4 v0 = hp1[0], v1 = hp1[1];
        float4 w0 = hp2[0], w1 = hp2[1];
        float4 x0 = hp3[0], x1 = hp3[1];
        float nm0 = nlut[pk0 >> 22], nm1 = nlut[pk1 >> 22];
        float nm2 = nlut[pk2 >> 22], nm3 = nlut[pk3 >> 22];
        const f16x2* wp0 = wc + ((pk0 >> 17) & 31) * 8;
        const f16x2* wp1 = wc + ((pk1 >> 17) & 31) * 8;
        const f16x2* wp2 = wc + ((pk2 >> 17) & 31) * 8;
        const f16x2* wp3 = wc + ((pk3 >> 17) & 31) * 8;
        float s0 = 0.f, s1 = 0.f, s2 = 0.f, s3 = 0.f;
        s0 = FDOT2(asf16x2(u0.x), wp0[0], s0);
        s0 = FDOT2(asf16x2(u0.y), wp0[1], s0);
        s0 = FDOT2(asf16x2(u0.z), wp0[2], s0);
        s0 = FDOT2(asf16x2(u0.w), wp0[3], s0);
        s0 = FDOT2(asf16x2(u1.x), wp0[4], s0);
        s0 = FDOT2(asf16x2(u1.y), wp0[5], s0);
        s0 = FDOT2(asf16x2(u1.z), wp0[6], s0);
        s0 = FDOT2(asf16x2(u1.w), wp0[7], s0);
        s1 = FDOT2(asf16x2(v0.x), wp1[0], s1);
        s1 = FDOT2(asf16x2(v0.y), wp1[1], s1);
        s1 = FDOT2(asf16x2(v0.z), wp1[2], s1);
        s1 = FDOT2(asf16x2(v0.w), wp1[3], s1);
        s1 = FDOT2(asf16x2(v1.x), wp1[4], s1);
        s1 = FDOT2(asf16x2(v1.y), wp1[5], s1);
        s1 = FDOT2(asf16x2(v1.z), wp1[6], s1);
        s1 = FDOT2(asf16x2(v1.w), wp1[7], s1);
        s2 = FDOT2(asf16x2(w0.x), wp2[0], s2);
        s2 = FDOT2(asf16x2(w0.y), wp2[1], s2);
        s2 = FDOT2(asf16x2(w0.z), wp2[2], s2);
        s2 = FDOT2(asf16x2(w0.w), wp2[3], s2);
        s2 = FDOT2(asf16x2(w1.x), wp2[4], s2);
        s2 = FDOT2(asf16x2(w1.y), wp2[5], s2);
        s2 = FDOT2(asf16x2(w1.z), wp2[6], s2);
        s2 = FDOT2(asf16x2(w1.w), wp2[7], s2);
        s3 = FDOT2(asf16x2(x0.x), wp3[0], s3);
        s3 = FDOT2(asf16x2(x0.y), wp3[1], s3);
        s3 = FDOT2(asf16x2(x0.z), wp3[2], s3);
        s3 = FDOT2(asf16x2(x0.w), wp3[3], s3);
        s3 = FDOT2(asf16x2(x1.x), wp3[4], s3);
        s3 = FDOT2(asf16x2(x1.y), wp3[5], s3);
        s3 = FDOT2(asf16x2(x1.z), wp3[6], s3);
        s3 = FDOT2(asf16x2(x1.w), wp3[7], s3);
        acc0 += nm0 * s0;
        acc1 += nm1 * s1;
        acc2 += nm2 * s2;
        acc3 += nm3 * s3;
    }
    for (; i < end; ++i) {
        unsigned pk = elist[i];
        const float4* hp = (const float4*)(h + (size_t)(pk & 0x1FFFF) * HDIM);
        float4 u0 = hp[0], u1 = hp[1];
        float nm = nlut[pk >> 22];
        const f16x2* wp = wc + ((pk >> 17) & 31) * 8;
        float sd = 0.f;
        sd = FDOT2(asf16x2(u0.x), wp[0], sd);
        sd = FDOT2(asf16x2(u0.y), wp[1], sd);
        sd = FDOT2(asf16x2(u0.z), wp[2], sd);
        sd = FDOT2(asf16x2(u0.w), wp[3], sd);
        sd = FDOT2(asf16x2(u1.x), wp[4], sd);
        sd = FDOT2(asf16x2(u1.y), wp[5], sd);
        sd = FDOT2(asf16x2(u1.z), wp[6], sd);
        sd = FDOT2(asf16x2(u1.w), wp[7], sd);
        acc0 += nm * sd;
    }
    float acc = (acc0 + acc1) + (acc2 + acc3);
    float m = acc;
    #pragma unroll
    for (int mask = 1; mask < 8; mask <<= 1)
        m = fmaxf(m, __shfl_xor(m, mask, 8));
    float ex = expf(acc - m);
    float ssumv = ex;
    #pragma unroll
    for (int mask = 1; mask < 8; mask <<= 1)
        ssumv += __shfl_xor(ssumv, mask, 8);
    out[(size_t)d * CDIM + c] = acc - m - logf(ssumv);
}

extern "C" void kernel_launch(void* const* d_in, const int* in_sizes, int n_in,
                              void* d_out, int out_size, void* d_ws, size_t ws_size,
                              hipStream_t stream) {
    const float* emb = (const float*)d_in[0];
    const float* W1  = (const float*)d_in[1];
    const float* W2  = (const float*)d_in[2];
    const int* ei    = (const int*)d_in[3];
    const int* et    = (const int*)d_in[4];
    const int* srcp  = ei;
    const int* dstp  = ei + E_EDGES;

    char* ws = (char*)d_ws;
    size_t off = 0;
    #define ALIGN256(x) (((x) + 255) & ~(size_t)255)
    int* gcursor     = (int*)(ws + off); off = ALIGN256(off + 512 * 4);
    int* bucketstart = (int*)(ws + off); off = ALIGN256(off + 512 * 4);
    int* rowstart    = (int*)(ws + off); off = ALIGN256(off + ((size_t)N_NODES + 8) * 4);
    unsigned int* ebuf  = (unsigned int*)(ws + off); off = ALIGN256(off + (size_t)NBUCK * CAP * 4);
    unsigned int* elist = (unsigned int*)(ws + off); off = ALIGN256(off + (size_t)E_EDGES * 4);
    unsigned short* BmT  = (unsigned short*)(ws + off); off = ALIGN256(off + (size_t)NOUT * F_IN * 2);
    unsigned short* ebf  = (unsigned short*)(ws + off); off = ALIGN256(off + (size_t)M_PAD * F_IN * 2);
    unsigned short* xw1  = (unsigned short*)(ws + off); off = ALIGN256(off + (size_t)M_PAD * NOUT * 2);
    _Float16* h          = (_Float16*)(ws + off);       off = ALIGN256(off + (size_t)N_NODES * HDIM * 2);
    float* out = (float*)d_out;

    hipMemsetAsync(gcursor, 0, 512 * 4, stream);

    k_front<<<FRONT_GRID, 512, 0, stream>>>(srcp, dstp, et, emb, W1, gcursor, ebuf, ebf, BmT);
    k_scanb<<<1, 512, 0, stream>>>(gcursor, bucketstart, rowstart);
    k_mid<<<MID_GRID, 256, 0, stream>>>(ebuf, gcursor, bucketstart, rowstart, elist, ebf, BmT, xw1);
    k_gather1<<<(N_NODES + 31) / 32, 256, 0, stream>>>(rowstart, elist, xw1, h);
    k_gather2<<<(N_NODES + 31) / 32, 256, 0, stream>>>(rowstart, elist, h, W2, out);
}